// Round 1
// 208.461 us; speedup vs baseline: 1.0071x; 1.0071x over previous
//
#include <hip/hip_runtime.h>
#include <hip/hip_bf16.h>
#include <math.h>

// Problem dims (fixed)
#define C_IN 256
#define HW 128          // H = W = 128
#define NPIX (HW*HW)    // 16384
#define DIM_LOI 128
#define N_LINES 16000
#define N_PAD 16128     // 63*256 : M padded for 256-tile GEMM
#define N_PTS0 32
#define N_PTS1 8
#define DIM_FC 1024
#define N_LABELS 3

typedef __attribute__((ext_vector_type(8))) short short8;   // 8 bf16 = 4 VGPRs
typedef __attribute__((ext_vector_type(4))) float f32x4;

// ---------------------------------------------------------------------------
// prep_kernel: all input conversions in ONE dispatch (branch on blockIdx).
//  [0,1024)    : transpose+bf16 features (256,16384) -> featsT (16384,256)
//  [1024,2048) : permute_w1  k=c*8+p -> k'=p*128+c, fp32->bf16
//  [2048,3072) : to_bf16 w2
//  [3072,3104) : to_bf16 w_fc1
// ---------------------------------------------------------------------------
__global__ __launch_bounds__(256) void prep_kernel(
    const float* __restrict__ feats, __hip_bfloat16* __restrict__ featsT,
    const float* __restrict__ w1,    __hip_bfloat16* __restrict__ w1p,
    const float* __restrict__ w2,    __hip_bfloat16* __restrict__ w2b,
    const float* __restrict__ wfc1,  __hip_bfloat16* __restrict__ wfc1b)
{
    __shared__ float tile[64][65];
    const int b = blockIdx.x;
    const int t = threadIdx.x;

    if (b < 1024) {
        // ---- transpose features ----
        const int p0 = (b & 255) * 64;
        const int c0 = (b >> 8) * 64;
#pragma unroll
        for (int i = 0; i < 4; ++i) {
            int c = (t >> 4) + i * 16;
            int p4 = (t & 15) * 4;
            float4 v = *(const float4*)(feats + (size_t)(c0 + c) * NPIX + p0 + p4);
            tile[c][p4 + 0] = v.x;
            tile[c][p4 + 1] = v.y;
            tile[c][p4 + 2] = v.z;
            tile[c][p4 + 3] = v.w;
        }
        __syncthreads();
#pragma unroll
        for (int i = 0; i < 2; ++i) {
            int p = (t >> 3) + i * 32;
            int cc = (t & 7) * 8;
            union { __hip_bfloat16 h[8]; uint4 u4; } pk;
#pragma unroll
            for (int j = 0; j < 8; ++j) pk.h[j] = __float2bfloat16(tile[cc + j][p]);
            *(uint4*)(featsT + (size_t)(p0 + p) * C_IN + c0 + cc) = pk.u4;
        }
    } else if (b < 2048) {
        // ---- permute w1 row ----
        float* row = &tile[0][0];
        const int n = b - 1024;
        ((float4*)row)[t] = ((const float4*)(w1 + (size_t)n * 1024))[t];
        __syncthreads();
        unsigned int* dst = (unsigned int*)(w1p + (size_t)n * 1024);
#pragma unroll
        for (int pass = 0; pass < 2; ++pass) {
            int j = pass * 256 + t;
            int k0 = 2 * j, k1 = 2 * j + 1;
            float v0 = row[(k0 & 127) * 8 + (k0 >> 7)];
            float v1 = row[(k1 & 127) * 8 + (k1 >> 7)];
            union { __hip_bfloat16 h[2]; unsigned int u; } pk;
            pk.h[0] = __float2bfloat16(v0);
            pk.h[1] = __float2bfloat16(v1);
            dst[j] = pk.u;
        }
    } else if (b < 3072) {
        int i = (b - 2048) * 256 + t;     // float4 index into w2
        float4 v = *(const float4*)(w2 + (size_t)i * 4);
        union { __hip_bfloat16 h[4]; uint2 u; } pk;
        pk.h[0] = __float2bfloat16(v.x);
        pk.h[1] = __float2bfloat16(v.y);
        pk.h[2] = __float2bfloat16(v.z);
        pk.h[3] = __float2bfloat16(v.w);
        *(uint2*)(w2b + (size_t)i * 4) = pk.u;
    } else {
        int i = (b - 3072) * 256 + t;     // float4 index into w_fc1 (8192 total)
        float4 v = *(const float4*)(wfc1 + (size_t)i * 4);
        union { __hip_bfloat16 h[4]; uint2 u; } pk;
        pk.h[0] = __float2bfloat16(v.x);
        pk.h[1] = __float2bfloat16(v.y);
        pk.h[2] = __float2bfloat16(v.z);
        pk.h[3] = __float2bfloat16(v.w);
        *(uint2*)(wfc1b + (size_t)i * 4) = pk.u;
    }
}

// ---------------------------------------------------------------------------
// Line pool v4 + zero-pad. 256 thr = 2 lines x 2 waves. Blocks whose lines
// are >= N_LINES write zero rows (pads featb to N_PAD rows for 256-tile GEMM).
// feat layout k' = p*128 + c (matches permuted w1).
// ---------------------------------------------------------------------------
__global__ __launch_bounds__(256) void pool_kernel(
    const __hip_bfloat16* __restrict__ loi,   // (NPIX, 128) bf16 channel-last
    const float* __restrict__ lines,          // (N_LINES, 4)
    __hip_bfloat16* __restrict__ feat)        // (N_PAD, 1024), k' = p*128+c
{
    __shared__ int   offs[2][N_PTS0][4];      // uint4-index base (pix*16)
    __shared__ float wts[2][N_PTS0][4];
    const int h     = threadIdx.x >> 7;  // line half of block (0,1)
    const int lt    = threadIdx.x & 127; // thread within line
    const int point = lt >> 4;           // 0..7 output point
    const int t16   = lt & 15;           // channel group 8*t16..8*t16+7
    const int l     = blockIdx.x * 2 + h;

    if (l >= N_LINES) {                  // zero-pad rows [N_LINES, N_PAD)
        uint4 z = {0u, 0u, 0u, 0u};
        uint4* fw = (uint4*)(feat + (size_t)l * (N_PTS1 * DIM_LOI));
        fw[point * 16 + t16] = z;
        return;                          // whole block takes this path (uniform)
    }

    if (lt < N_PTS0) {
        int j = lt;
        float tt = (float)j * (1.0f / 31.0f);
        float U0 = lines[4 * l + 0], U1 = lines[4 * l + 1];
        float V0 = lines[4 * l + 2], V1 = lines[4 * l + 3];
        float px = U0 * tt + V0 * (1.0f - tt) - 0.5f;
        float py = U1 * tt + V1 * (1.0f - tt) - 0.5f;
        float px0 = fminf(fmaxf(floorf(px), 0.0f), 127.0f);
        float py0 = fminf(fmaxf(floorf(py), 0.0f), 127.0f);
        float px1 = fminf(fmaxf(px0 + 1.0f, 0.0f), 127.0f);
        float py1 = fminf(fmaxf(py0 + 1.0f, 0.0f), 127.0f);
        int ix0 = (int)px0, iy0 = (int)py0, ix1 = (int)px1, iy1 = (int)py1;
        float wx0 = px1 - px, wx1 = px - px0;
        float wy0 = py1 - py, wy1 = py - py0;
        offs[h][j][0] = (iy0 * HW + ix0) * 16;
        offs[h][j][1] = (iy1 * HW + ix0) * 16;
        offs[h][j][2] = (iy0 * HW + ix1) * 16;
        offs[h][j][3] = (iy1 * HW + ix1) * 16;
        wts[h][j][0] = wy0 * wx0;
        wts[h][j][1] = wy1 * wx0;
        wts[h][j][2] = wy0 * wx1;
        wts[h][j][3] = wy1 * wx1;
    }
    __syncthreads();

    const uint4* loi4 = (const uint4*)loi;
    uint4* featw = (uint4*)(feat + (size_t)l * (N_PTS1 * DIM_LOI));

    float b0 = -INFINITY, b1 = -INFINITY, b2 = -INFINITY, b3 = -INFINITY;
    float b4 = -INFINITY, b5 = -INFINITY, b6 = -INFINITY, b7 = -INFINITY;
#pragma unroll
    for (int q = 0; q < 4; ++q) {
        int j = point * 4 + q;
        uint4 v0 = loi4[offs[h][j][0] + t16];
        uint4 v1 = loi4[offs[h][j][1] + t16];
        uint4 v2 = loi4[offs[h][j][2] + t16];
        uint4 v3 = loi4[offs[h][j][3] + t16];
        float w0 = wts[h][j][0], w1 = wts[h][j][1];
        float w2 = wts[h][j][2], w3 = wts[h][j][3];
        float s;
        s = w0 * __uint_as_float(v0.x << 16) + w1 * __uint_as_float(v1.x << 16)
          + w2 * __uint_as_float(v2.x << 16) + w3 * __uint_as_float(v3.x << 16);
        b0 = fmaxf(b0, s);
        s = w0 * __uint_as_float(v0.x & 0xffff0000u) + w1 * __uint_as_float(v1.x & 0xffff0000u)
          + w2 * __uint_as_float(v2.x & 0xffff0000u) + w3 * __uint_as_float(v3.x & 0xffff0000u);
        b1 = fmaxf(b1, s);
        s = w0 * __uint_as_float(v0.y << 16) + w1 * __uint_as_float(v1.y << 16)
          + w2 * __uint_as_float(v2.y << 16) + w3 * __uint_as_float(v3.y << 16);
        b2 = fmaxf(b2, s);
        s = w0 * __uint_as_float(v0.y & 0xffff0000u) + w1 * __uint_as_float(v1.y & 0xffff0000u)
          + w2 * __uint_as_float(v2.y & 0xffff0000u) + w3 * __uint_as_float(v3.y & 0xffff0000u);
        b3 = fmaxf(b3, s);
        s = w0 * __uint_as_float(v0.z << 16) + w1 * __uint_as_float(v1.z << 16)
          + w2 * __uint_as_float(v2.z << 16) + w3 * __uint_as_float(v3.z << 16);
        b4 = fmaxf(b4, s);
        s = w0 * __uint_as_float(v0.z & 0xffff0000u) + w1 * __uint_as_float(v1.z & 0xffff0000u)
          + w2 * __uint_as_float(v2.z & 0xffff0000u) + w3 * __uint_as_float(v3.z & 0xffff0000u);
        b5 = fmaxf(b5, s);
        s = w0 * __uint_as_float(v0.w << 16) + w1 * __uint_as_float(v1.w << 16)
          + w2 * __uint_as_float(v2.w << 16) + w3 * __uint_as_float(v3.w << 16);
        b6 = fmaxf(b6, s);
        s = w0 * __uint_as_float(v0.w & 0xffff0000u) + w1 * __uint_as_float(v1.w & 0xffff0000u)
          + w2 * __uint_as_float(v2.w & 0xffff0000u) + w3 * __uint_as_float(v3.w & 0xffff0000u);
        b7 = fmaxf(b7, s);
    }
    union { __hip_bfloat16 hh[8]; uint4 u; } pk;
    pk.hh[0] = __float2bfloat16(b0);
    pk.hh[1] = __float2bfloat16(b1);
    pk.hh[2] = __float2bfloat16(b2);
    pk.hh[3] = __float2bfloat16(b3);
    pk.hh[4] = __float2bfloat16(b4);
    pk.hh[5] = __float2bfloat16(b5);
    pk.hh[6] = __float2bfloat16(b6);
    pk.hh[7] = __float2bfloat16(b7);
    featw[point * 16 + t16] = pk.u;   // elements point*128 + 8*t16 ..+7
}

// ---------------------------------------------------------------------------
// MFMA bf16 GEMM, 128x128 tile, BK=64 dbuf (R12 structure). KEPT for the
// conv1x1 GEMM only (N=128 can't take a 256-wide tile).
// ---------------------------------------------------------------------------
__global__ __launch_bounds__(256) void mfma_gemm(
    const __hip_bfloat16* __restrict__ A,   // (M, K) row-major
    const __hip_bfloat16* __restrict__ B,   // (N, K) row-major (= B^T)
    const float* __restrict__ bias,         // (N)
    __hip_bfloat16* __restrict__ out,       // (M, N)
    int M, int N, int K, int n_tiles)
{
    __shared__ __hip_bfloat16 As[2][128 * 64];   // 32 KB
    __shared__ __hip_bfloat16 Bs[2][128 * 64];   // 32 KB
    const int tid  = threadIdx.x;
    const int lane = tid & 63;
    const int wave = tid >> 6;
    const int wr = wave >> 1, wc = wave & 1;    // 2x2 wave grid
    const int quad = lane >> 4;
    const int l16  = lane & 15;

    // XCD-aware relabel (grid must be divisible by 8)
    const int lid = blockIdx.x;
    const int per = gridDim.x >> 3;
    const int g   = (lid & 7) * per + (lid >> 3);
    const int n0 = (g % n_tiles) * 128;
    const int m0 = (g / n_tiles) * 128;

    f32x4 acc[4][4];
#pragma unroll
    for (int i = 0; i < 4; ++i)
#pragma unroll
        for (int j = 0; j < 4; ++j) { f32x4 z = {0.f, 0.f, 0.f, 0.f}; acc[i][j] = z; }

    auto stage = [&](int k0, int buf) {
#pragma unroll
        for (int s = 0; s < 4; ++s) {
            int li   = s * 256 + tid;          // chunk 0..1023
            int row  = (li & 511) >> 2;        // 0..127
            int ke   = (li >> 9) * 32 + (li & 3) * 8;  // k element offset 0..63
            const __hip_bfloat16* ga = A + (size_t)(m0 + row) * K + k0 + ke;
            const __hip_bfloat16* gb = B + (size_t)(n0 + row) * K + k0 + ke;
            int chunk = s * 256 + (tid & ~63); // wave-uniform base chunk
            __builtin_amdgcn_global_load_lds(
                (const __attribute__((address_space(1))) unsigned int*)ga,
                (__attribute__((address_space(3))) unsigned int*)(As[buf] + chunk * 8),
                16, 0, 0);
            __builtin_amdgcn_global_load_lds(
                (const __attribute__((address_space(1))) unsigned int*)gb,
                (__attribute__((address_space(3))) unsigned int*)(Bs[buf] + chunk * 8),
                16, 0, 0);
        }
    };

    const int nk = K >> 6;
    stage(0, 0);
    __syncthreads();                 // buffer 0 ready

    for (int kt = 0; kt < nk; ++kt) {
        const int cur = kt & 1;
        if (kt + 1 < nk) stage((kt + 1) << 6, cur ^ 1);   // async prefetch

#pragma unroll
        for (int kh = 0; kh < 2; ++kh) {
            const short* ap = (const short*)As[cur] + kh * 4096;
            const short* bp = (const short*)Bs[cur] + kh * 4096;
            short8 af[4], bf[4];
#pragma unroll
            for (int mt = 0; mt < 4; ++mt) {
                int row = wr * 64 + mt * 16 + l16;
                af[mt] = *(const short8*)(ap + row * 32 + quad * 8);
            }
#pragma unroll
            for (int nt = 0; nt < 4; ++nt) {
                int row = wc * 64 + nt * 16 + l16;
                bf[nt] = *(const short8*)(bp + row * 32 + quad * 8);
            }
#pragma unroll
            for (int mt = 0; mt < 4; ++mt)
#pragma unroll
                for (int nt = 0; nt < 4; ++nt)
                    acc[mt][nt] = __builtin_amdgcn_mfma_f32_16x16x32_bf16(
                        af[mt], bf[nt], acc[mt][nt], 0, 0, 0);
        }
        __syncthreads();
    }

#pragma unroll
    for (int nt = 0; nt < 4; ++nt) {
        int n = n0 + wc * 64 + nt * 16 + l16;
        float bv = bias[n];
#pragma unroll
        for (int mt = 0; mt < 4; ++mt) {
            int mbase = m0 + wr * 64 + mt * 16 + quad * 4;
#pragma unroll
            for (int r = 0; r < 4; ++r) {
                float v = acc[mt][nt][r] + bv;
                v = v > 0.0f ? v : 0.0f;
                out[(size_t)(mbase + r) * N + n] = (__hip_bfloat16)v;
            }
        }
    }
}

// ---------------------------------------------------------------------------
// mfma_gemm256: 256x256 tile, BK=64, 8-phase counted-vmcnt schedule
// (T2+T3+T4+T5 port). 512 thr = 8 waves (2M x 4N); per-wave 128x64 output
// = acc[8][4] of 16x16 frags; interleaved wave->row map (wave wr owns rows
// wr*64..+63 and 128+wr*64..+63) so A-half0 (tile rows 0-127) is fully
// ds-read in ONE phase.
//
// LDS 128 KiB: [A buf0 | A buf1 | B buf0 | B buf1], each 256x64 bf16 (32KB).
// k-byte swizzle koff ^= (row&3)<<5 (bits 5-6) cuts the 16-way ds_read_b128
// conflict to 4-way; applied by pre-swizzling the global SOURCE address in
// the stage (LDS dest stays linear, required by global_load_lds) and by the
// same XOR on the read side.
//
// Phase table per iteration (tiles 2it -> buf0 phases 1-4, 2it+1 -> buf1
// phases 5-8). "reads" = ds_read regions, "stage" = one 16KB half-tile
// (2 x global_load_lds x 512 thr):
//   p1: read A0(buf0)+Bn01(buf0)   stage B1(2it+1)->buf1   [B1' was free @p6 prev]
//   p2: read Bn23(buf0)            stage A0(2it+2)->buf0   [A-half0 free @p1]
//   p3: read A1(buf0)              stage B0(2it+2)->buf0   [B free @p2]
//   p4: --                         stage A1(2it+2)->buf0   [A-half1 free @p3]
//       vmcnt(6) (3 half-tiles in flight) -> tile 2it+1 fully landed
//   p5: read A0(buf1)+Bn01(buf1)   stage B1(2it+2)->buf0   [B-half1 free @p2]
//   p6: read Bn23(buf1)            stage A0(2it+3)->buf1   [free @p5]
//   p7: read A1(buf1)              stage B0(2it+3)->buf1   [free @p6]
//   p8: --                         stage A1(2it+3)->buf1   [free @p7]
//       vmcnt(6) -> tile 2it+2 fully landed
// Every in-flight stage target is disjoint from every live read region;
// per-wave lgkmcnt(0) before MFMA + end-of-phase barrier orders read-complete
// before the next phase's stage issue. Requires K%128==0, K>=256, M%256==0.
// ---------------------------------------------------------------------------
__global__ __launch_bounds__(512, 2) void mfma_gemm256(
    const __hip_bfloat16* __restrict__ A,   // (M, K) row-major, M % 256 == 0
    const __hip_bfloat16* __restrict__ B,   // (N, K) row-major (= B^T)
    const float* __restrict__ bias,         // (N)
    __hip_bfloat16* __restrict__ out,       // (M, N)
    int M, int N, int K, int n_tiles)
{
    __shared__ __align__(16) short smem[65536];   // 128 KB
    const int tid  = threadIdx.x;
    const int lane = tid & 63;
    const int wave = tid >> 6;              // 0..7
    const int wr   = wave >> 2;             // 0..1 (M wave)
    const int wc   = wave & 3;              // 0..3 (N wave)
    const int quad = lane >> 4;
    const int l16  = lane & 15;

    const int g  = blockIdx.x;
    const int n0 = (g % n_tiles) * 256;
    const int m0 = (g / n_tiles) * 256;

    // LDS short offsets: A buf b @ b*16384 ; B buf b @ 32768 + b*16384.
    // Half-tile h of a tile = +h*8192.

    // stage one half-tile (128 rows x 64 k bf16): 2 x 16B per thread,
    // linear LDS dest (uniform base + lane*16), swizzled global source.
    auto stageHalf = [&](int dstBase, const __hip_bfloat16* G, int rowG0, int k0) {
#pragma unroll
        for (int j = 0; j < 2; ++j) {
            const int c   = j * 512 + tid;        // chunk 0..1023
            const int row = c >> 3;               // 0..127 (row within half)
            const int kb  = (c & 7) << 4;         // byte 0..112 within row
            const int kbl = kb ^ ((row & 3) << 5);// logical k-byte for this slot
            const __hip_bfloat16* src = G + (size_t)(rowG0 + row) * K + k0 + (kbl >> 1);
            const short* dst = smem + dstBase + j * 4096 + (wave << 9); // wave-uniform
            __builtin_amdgcn_global_load_lds(
                (const __attribute__((address_space(1))) unsigned int*)src,
                (__attribute__((address_space(3))) unsigned int*)dst, 16, 0, 0);
        }
    };

    // fragment reads (swizzle-matched)
    auto ldA = [&](int buf, int mt, int ks) -> short8 {
        int r    = ((mt >> 2) << 7) + (wr << 6) + ((mt & 3) << 4) + l16;
        int koff = ((ks << 6) + (quad << 4)) ^ ((l16 & 3) << 5);
        return *(const short8*)(smem + buf * 16384 + r * 64 + (koff >> 1));
    };
    auto ldB = [&](int buf, int nt, int ks) -> short8 {
        int r    = (wc << 6) + (nt << 4) + l16;
        int koff = ((ks << 6) + (quad << 4)) ^ ((l16 & 3) << 5);
        return *(const short8*)(smem + 32768 + buf * 16384 + r * 64 + (koff >> 1));
    };

    f32x4 acc[8][4];
#pragma unroll
    for (int i = 0; i < 8; ++i)
#pragma unroll
        for (int j = 0; j < 4; ++j) { f32x4 z = {0.f, 0.f, 0.f, 0.f}; acc[i][j] = z; }

    short8 af[4][2], b01[2][2], b23[2][2];

    const int NT2 = K >> 7;   // iterations of 2 k-tiles; requires NT2 >= 2

    // ---- prologue: tile0 -> buf0 (4 halves), tile1 -> buf1 (A0,B0,A1) ----
    stageHalf(0,                 A, m0,       0);    // A0 t0
    stageHalf(32768,             B, n0,       0);    // B0 t0
    stageHalf(8192,              A, m0 + 128, 0);    // A1 t0
    stageHalf(32768 + 8192,      B, n0 + 128, 0);    // B1 t0
    stageHalf(16384,             A, m0,       64);   // A0 t1
    stageHalf(32768 + 16384,     B, n0,       64);   // B0 t1
    stageHalf(16384 + 8192,      A, m0 + 128, 64);   // A1 t1
    asm volatile("s_waitcnt vmcnt(6)" ::: "memory"); // tile0 landed, t1 in flight
    __builtin_amdgcn_sched_barrier(0);
    __builtin_amdgcn_s_barrier();

#pragma unroll 1
    for (int it = 0; it < NT2; ++it) {
        const bool more = (it + 1 < NT2);
        const int kc1 = (2 * it + 1) << 6;   // buf1 current tile k-base
        const int kn0 = (2 * it + 2) << 6;   // next buf0 tile
        const int kn1 = (2 * it + 3) << 6;   // next buf1 tile

        // ---------- p1: buf0 (m0-3 x n0-1) ----------
#pragma unroll
        for (int mt = 0; mt < 4; ++mt) { af[mt][0] = ldA(0, mt, 0); af[mt][1] = ldA(0, mt, 1); }
#pragma unroll
        for (int nt = 0; nt < 2; ++nt) { b01[nt][0] = ldB(0, nt, 0); b01[nt][1] = ldB(0, nt, 1); }
        stageHalf(32768 + 16384 + 8192, B, n0 + 128, kc1);    // B1 of buf1 tile
        __builtin_amdgcn_s_barrier();
        asm volatile("s_waitcnt lgkmcnt(0)" ::: "memory");
        __builtin_amdgcn_sched_barrier(0);
        __builtin_amdgcn_s_setprio(1);
#pragma unroll
        for (int ks = 0; ks < 2; ++ks)
#pragma unroll
            for (int mt = 0; mt < 4; ++mt)
#pragma unroll
                for (int nt = 0; nt < 2; ++nt)
                    acc[mt][nt] = __builtin_amdgcn_mfma_f32_16x16x32_bf16(
                        af[mt][ks], b01[nt][ks], acc[mt][nt], 0, 0, 0);
        __builtin_amdgcn_s_setprio(0);
        __builtin_amdgcn_s_barrier();

        // ---------- p2: buf0 (m0-3 x n2-3) ----------
#pragma unroll
        for (int nt = 0; nt < 2; ++nt) { b23[nt][0] = ldB(0, nt + 2, 0); b23[nt][1] = ldB(0, nt + 2, 1); }
        if (more) stageHalf(0, A, m0, kn0);                   // A0 next -> buf0
        __builtin_amdgcn_s_barrier();
        asm volatile("s_waitcnt lgkmcnt(0)" ::: "memory");
        __builtin_amdgcn_sched_barrier(0);
        __builtin_amdgcn_s_setprio(1);
#pragma unroll
        for (int ks = 0; ks < 2; ++ks)
#pragma unroll
            for (int mt = 0; mt < 4; ++mt)
#pragma unroll
                for (int nt = 0; nt < 2; ++nt)
                    acc[mt][nt + 2] = __builtin_amdgcn_mfma_f32_16x16x32_bf16(
                        af[mt][ks], b23[nt][ks], acc[mt][nt + 2], 0, 0, 0);
        __builtin_amdgcn_s_setprio(0);
        __builtin_amdgcn_s_barrier();

        // ---------- p3: buf0 (m4-7 x n0-1) ----------
#pragma unroll
        for (int mt = 0; mt < 4; ++mt) { af[mt][0] = ldA(0, mt + 4, 0); af[mt][1] = ldA(0, mt + 4, 1); }
        if (more) stageHalf(32768, B, n0, kn0);               // B0 next -> buf0
        __builtin_amdgcn_s_barrier();
        asm volatile("s_waitcnt lgkmcnt(0)" ::: "memory");
        __builtin_amdgcn_sched_barrier(0);
        __builtin_amdgcn_s_setprio(1);
#pragma unroll
        for (int ks = 0; ks < 2; ++ks)
#pragma unroll
            for (int mt = 0; mt < 4; ++mt)
#pragma unroll
                for (int nt = 0; nt < 2; ++nt)
                    acc[mt + 4][nt] = __builtin_amdgcn_mfma_f32_16x16x32_bf16(
                        af[mt][ks], b01[nt][ks], acc[mt + 4][nt], 0, 0, 0);
        __builtin_amdgcn_s_setprio(0);
        __builtin_amdgcn_s_barrier();

        // ---------- p4: buf0 (m4-7 x n2-3) + K-tile drain ----------
        if (more) stageHalf(8192, A, m0 + 128, kn0);          // A1 next -> buf0
        __builtin_amdgcn_s_barrier();
        asm volatile("s_waitcnt lgkmcnt(0)" ::: "memory");
        __builtin_amdgcn_sched_barrier(0);
        __builtin_amdgcn_s_setprio(1);
#pragma unroll
        for (int ks = 0; ks < 2; ++ks)
#pragma unroll
            for (int mt = 0; mt < 4; ++mt)
#pragma unroll
                for (int nt = 0; nt < 2; ++nt)
                    acc[mt + 4][nt + 2] = __builtin_amdgcn_mfma_f32_16x16x32_bf16(
                        af[mt][ks], b23[nt][ks], acc[mt + 4][nt + 2], 0, 0, 0);
        __builtin_amdgcn_s_setprio(0);
        if (more) { asm volatile("s_waitcnt vmcnt(6)" ::: "memory"); }
        else      { asm volatile("s_waitcnt vmcnt(0)" ::: "memory"); }
        __builtin_amdgcn_sched_barrier(0);
        __builtin_amdgcn_s_barrier();    // buf1 tile (2it+1) fully landed

        // ---------- p5: buf1 (m0-3 x n0-1) ----------
#pragma unroll
        for (int mt = 0; mt < 4; ++mt) { af[mt][0] = ldA(1, mt, 0); af[mt][1] = ldA(1, mt, 1); }
#pragma unroll
        for (int nt = 0; nt < 2; ++nt) { b01[nt][0] = ldB(1, nt, 0); b01[nt][1] = ldB(1, nt, 1); }
        if (more) stageHalf(32768 + 8192, B, n0 + 128, kn0);  // B1 next -> buf0
        __builtin_amdgcn_s_barrier();
        asm volatile("s_waitcnt lgkmcnt(0)" ::: "memory");
        __builtin_amdgcn_sched_barrier(0);
        __builtin_amdgcn_s_setprio(1);
#pragma unroll
        for (int ks = 0; ks < 2; ++ks)
#pragma unroll
            for (int mt = 0; mt < 4; ++mt)
#pragma unroll
                for (int nt = 0; nt < 2; ++nt)
                    acc[mt][nt] = __builtin_amdgcn_mfma_f32_16x16x32_bf16(
                        af[mt][ks], b01[nt][ks], acc[mt][nt], 0, 0, 0);
        __builtin_amdgcn_s_setprio(0);
        __builtin_amdgcn_s_barrier();

        // ---------- p6: buf1 (m0-3 x n2-3) ----------
#pragma unroll
        for (int nt = 0; nt < 2; ++nt) { b23[nt][0] = ldB(1, nt + 2, 0); b23[nt][1] = ldB(1, nt + 2, 1); }
        if (more) stageHalf(16384, A, m0, kn1);               // A0 next -> buf1
        __builtin_amdgcn_s_barrier();
        asm volatile("s_waitcnt lgkmcnt(0)" ::: "memory");
        __builtin_amdgcn_sched_barrier(0);
        __builtin_amdgcn_s_setprio(1);
#pragma unroll
        for (int ks = 0; ks < 2; ++ks)
#pragma unroll
            for (int mt = 0; mt < 4; ++mt)
#pragma unroll
                for (int nt = 0; nt < 2; ++nt)
                    acc[mt][nt + 2] = __builtin_amdgcn_mfma_f32_16x16x32_bf16(
                        af[mt][ks], b23[nt][ks], acc[mt][nt + 2], 0, 0, 0);
        __builtin_amdgcn_s_setprio(0);
        __builtin_amdgcn_s_barrier();

        // ---------- p7: buf1 (m4-7 x n0-1) ----------
#pragma unroll
        for (int mt = 0; mt < 4; ++mt) { af[mt][0] = ldA(1, mt + 4, 0); af[mt][1] = ldA(1, mt + 4, 1); }
        if (more) stageHalf(32768 + 16384, B, n0, kn1);       // B0 next -> buf1
        __builtin_amdgcn_s_barrier();
        asm volatile("s_waitcnt lgkmcnt(0)" ::: "memory");
        __builtin_amdgcn_sched_barrier(0);
        __builtin_amdgcn_s_setprio(1);
#pragma unroll
        for (int ks = 0; ks < 2; ++ks)
#pragma unroll
            for (int mt = 0; mt < 4; ++mt)
#pragma unroll
                for (int nt = 0; nt < 2; ++nt)
                    acc[mt + 4][nt] = __builtin_amdgcn_mfma_f32_16x16x32_bf16(
                        af[mt][ks], b01[nt][ks], acc[mt + 4][nt], 0, 0, 0);
        __builtin_amdgcn_s_setprio(0);
        __builtin_amdgcn_s_barrier();

        // ---------- p8: buf1 (m4-7 x n2-3) + K-tile drain ----------
        if (more) stageHalf(16384 + 8192, A, m0 + 128, kn1);  // A1 next -> buf1
        __builtin_amdgcn_s_barrier();
        asm volatile("s_waitcnt lgkmcnt(0)" ::: "memory");
        __builtin_amdgcn_sched_barrier(0);
        __builtin_amdgcn_s_setprio(1);
#pragma unroll
        for (int ks = 0; ks < 2; ++ks)
#pragma unroll
            for (int mt = 0; mt < 4; ++mt)
#pragma unroll
                for (int nt = 0; nt < 2; ++nt)
                    acc[mt + 4][nt + 2] = __builtin_amdgcn_mfma_f32_16x16x32_bf16(
                        af[mt][ks], b23[nt][ks], acc[mt + 4][nt + 2], 0, 0, 0);
        __builtin_amdgcn_s_setprio(0);
        if (more) {
            asm volatile("s_waitcnt vmcnt(6)" ::: "memory");  // buf0 tile (2it+2) landed
            __builtin_amdgcn_sched_barrier(0);
        }
        __builtin_amdgcn_s_barrier();
    }

    // ---- epilogue: bias + relu + store. frag row = quad*4 + r, col = l16 ----
#pragma unroll
    for (int nt = 0; nt < 4; ++nt) {
        int n = n0 + (wc << 6) + (nt << 4) + l16;
        float bv = bias[n];
#pragma unroll
        for (int mt = 0; mt < 8; ++mt) {
            int mbase = m0 + ((mt >> 2) << 7) + (wr << 6) + ((mt & 3) << 4) + (quad << 2);
#pragma unroll
            for (int r = 0; r < 4; ++r) {
                float v = acc[mt][nt][r] + bv;
                v = v > 0.0f ? v : 0.0f;
                out[(size_t)(mbase + r) * N + n] = (__hip_bfloat16)v;
            }
        }
    }
}

// ---------------------------------------------------------------------------
// Head: one wave per line, uint4 x-loads (16 B/lane, 2 iters):
// logits[l][n] = sum_k x2[l][k]*w3[n][k] + b3[n]
// ---------------------------------------------------------------------------
__global__ __launch_bounds__(256) void head_kernel(
    const __hip_bfloat16* __restrict__ x2,  // (N_LINES, 1024) bf16
    const float* __restrict__ w3,           // (3, 1024)
    const float* __restrict__ b3,           // (3)
    float* __restrict__ out)                // (N_LINES, 3)
{
    const int gtid = blockIdx.x * blockDim.x + threadIdx.x;
    const int l = gtid >> 6;
    const int lane = threadIdx.x & 63;
    if (l >= N_LINES) return;
    const __hip_bfloat16* xr = x2 + (size_t)l * DIM_FC;
    float s0 = 0.0f, s1 = 0.0f, s2 = 0.0f;
#pragma unroll
    for (int it = 0; it < 2; ++it) {
        int k = it * 512 + lane * 8;
        uint4 xv = *(const uint4*)(xr + k);
        float x[8];
        x[0] = __uint_as_float(xv.x << 16);
        x[1] = __uint_as_float(xv.x & 0xffff0000u);
        x[2] = __uint_as_float(xv.y << 16);
        x[3] = __uint_as_float(xv.y & 0xffff0000u);
        x[4] = __uint_as_float(xv.z << 16);
        x[5] = __uint_as_float(xv.z & 0xffff0000u);
        x[6] = __uint_as_float(xv.w << 16);
        x[7] = __uint_as_float(xv.w & 0xffff0000u);
#pragma unroll
        for (int h = 0; h < 2; ++h) {
            int kk = k + h * 4;
            float4 wa = *(const float4*)(w3 + 0 * DIM_FC + kk);
            float4 wb = *(const float4*)(w3 + 1 * DIM_FC + kk);
            float4 wc = *(const float4*)(w3 + 2 * DIM_FC + kk);
            s0 += x[h*4+0] * wa.x + x[h*4+1] * wa.y + x[h*4+2] * wa.z + x[h*4+3] * wa.w;
            s1 += x[h*4+0] * wb.x + x[h*4+1] * wb.y + x[h*4+2] * wb.z + x[h*4+3] * wb.w;
            s2 += x[h*4+0] * wc.x + x[h*4+1] * wc.y + x[h*4+2] * wc.z + x[h*4+3] * wc.w;
        }
    }
#pragma unroll
    for (int off = 32; off > 0; off >>= 1) {
        s0 += __shfl_xor(s0, off);
        s1 += __shfl_xor(s1, off);
        s2 += __shfl_xor(s2, off);
    }
    if (lane == 0) {
        out[(size_t)l * 3 + 0] = s0 + b3[0];
        out[(size_t)l * 3 + 1] = s1 + b3[1];
        out[(size_t)l * 3 + 2] = s2 + b3[2];
    }
}

// ---------------------------------------------------------------------------
extern "C" void kernel_launch(void* const* d_in, const int* in_sizes, int n_in,
                              void* d_out, int out_size, void* d_ws, size_t ws_size,
                              hipStream_t stream) {
    const float* features = (const float*)d_in[0];  // (1,256,128,128)
    const float* lines    = (const float*)d_in[1];  // (16000,4)
    const float* w_fc1    = (const float*)d_in[2];  // (128,256)
    const float* b_fc1    = (const float*)d_in[3];  // (128)
    const float* w1       = (const float*)d_in[4];  // (1024,1024)
    const float* b1       = (const float*)d_in[5];  // (1024)
    const float* w2       = (const float*)d_in[6];  // (1024,1024)
    const float* b2       = (const float*)d_in[7];  // (1024)
    const float* w3       = (const float*)d_in[8];  // (3,1024)
    const float* b3       = (const float*)d_in[9];  // (3)
    float* out = (float*)d_out;

    char* ws = (char*)d_ws;
    __hip_bfloat16* loi    = (__hip_bfloat16*)ws;
    __hip_bfloat16* featb  = (__hip_bfloat16*)(ws + (size_t)8 * 1024 * 1024);   // N_PAD x 1024
    __hip_bfloat16* x1b    = (__hip_bfloat16*)(ws + (size_t)40 * 1024 * 1024);  // N_PAD x 1024
    __hip_bfloat16* x2b    = featb;   // reuse (featb dead after GEMM1)
    __hip_bfloat16* w1b    = (__hip_bfloat16*)(ws + (size_t)72 * 1024 * 1024);
    __hip_bfloat16* w2b    = (__hip_bfloat16*)(ws + (size_t)74 * 1024 * 1024);
    __hip_bfloat16* featsT = (__hip_bfloat16*)(ws + (size_t)76 * 1024 * 1024);
    __hip_bfloat16* wfc1b  = (__hip_bfloat16*)(ws + (size_t)84 * 1024 * 1024);

    // 0) all prep in one dispatch
    prep_kernel<<<dim3(3104), 256, 0, stream>>>(
        features, featsT, w1, w1b, w2, w2b, w_fc1, wfc1b);

    // 1) conv1x1 as MFMA GEMM (128-tile kernel; N=128)
    mfma_gemm<<<dim3(NPIX / 128), 256, 0, stream>>>(
        featsT, wfc1b, b_fc1, loi, NPIX, DIM_LOI, C_IN, 1);

    // 2) line pooling -> featb (N_PAD,1024) bf16, rows >= N_LINES zeroed
    pool_kernel<<<dim3(N_PAD / 2), 256, 0, stream>>>(loi, lines, featb);

    // 3) x1 = relu(feat @ w1p^T + b1): 63 m-tiles x 4 n-tiles, 8-phase kernel
    mfma_gemm256<<<dim3((N_PAD / 256) * (DIM_FC / 256)), 512, 0, stream>>>(
        featb, w1b, b1, x1b, N_PAD, DIM_FC, DIM_FC, DIM_FC / 256);

    // 4) x2 = relu(x1 @ w2^T + b2)
    mfma_gemm256<<<dim3((N_PAD / 256) * (DIM_FC / 256)), 512, 0, stream>>>(
        x1b, w2b, b2, x2b, N_PAD, DIM_FC, DIM_FC, DIM_FC / 256);

    // 5) logits = x2 @ w3^T + b3
    head_kernel<<<dim3((N_LINES * 64 + 255) / 256), 256, 0, stream>>>(x2b, w3, b3, out);
}

// Round 2
// 196.299 us; speedup vs baseline: 1.0694x; 1.0620x over previous
//
#include <hip/hip_runtime.h>
#include <hip/hip_bf16.h>
#include <math.h>

// Problem dims (fixed)
#define C_IN 256
#define HW 128          // H = W = 128
#define NPIX (HW*HW)    // 16384
#define DIM_LOI 128
#define N_LINES 16000
#define N_PAD 16128     // 63*256 : M padded for 256-tile GEMM
#define N_PTS0 32
#define N_PTS1 8
#define DIM_FC 1024
#define N_LABELS 3

typedef __attribute__((ext_vector_type(8))) short short8;   // 8 bf16 = 4 VGPRs
typedef __attribute__((ext_vector_type(4))) float f32x4;

// ---------------------------------------------------------------------------
// prep_kernel: all input conversions in ONE dispatch (branch on blockIdx).
//  [0,1024)    : transpose+bf16 features (256,16384) -> featsT (16384,256)
//  [1024,2048) : permute_w1  k=c*8+p -> k'=p*128+c, fp32->bf16
//  [2048,3072) : to_bf16 w2
//  [3072,3104) : to_bf16 w_fc1
// ---------------------------------------------------------------------------
__global__ __launch_bounds__(256) void prep_kernel(
    const float* __restrict__ feats, __hip_bfloat16* __restrict__ featsT,
    const float* __restrict__ w1,    __hip_bfloat16* __restrict__ w1p,
    const float* __restrict__ w2,    __hip_bfloat16* __restrict__ w2b,
    const float* __restrict__ wfc1,  __hip_bfloat16* __restrict__ wfc1b)
{
    __shared__ float tile[64][65];
    const int b = blockIdx.x;
    const int t = threadIdx.x;

    if (b < 1024) {
        // ---- transpose features ----
        const int p0 = (b & 255) * 64;
        const int c0 = (b >> 8) * 64;
#pragma unroll
        for (int i = 0; i < 4; ++i) {
            int c = (t >> 4) + i * 16;
            int p4 = (t & 15) * 4;
            float4 v = *(const float4*)(feats + (size_t)(c0 + c) * NPIX + p0 + p4);
            tile[c][p4 + 0] = v.x;
            tile[c][p4 + 1] = v.y;
            tile[c][p4 + 2] = v.z;
            tile[c][p4 + 3] = v.w;
        }
        __syncthreads();
#pragma unroll
        for (int i = 0; i < 2; ++i) {
            int p = (t >> 3) + i * 32;
            int cc = (t & 7) * 8;
            union { __hip_bfloat16 h[8]; uint4 u4; } pk;
#pragma unroll
            for (int j = 0; j < 8; ++j) pk.h[j] = __float2bfloat16(tile[cc + j][p]);
            *(uint4*)(featsT + (size_t)(p0 + p) * C_IN + c0 + cc) = pk.u4;
        }
    } else if (b < 2048) {
        // ---- permute w1 row ----
        float* row = &tile[0][0];
        const int n = b - 1024;
        ((float4*)row)[t] = ((const float4*)(w1 + (size_t)n * 1024))[t];
        __syncthreads();
        unsigned int* dst = (unsigned int*)(w1p + (size_t)n * 1024);
#pragma unroll
        for (int pass = 0; pass < 2; ++pass) {
            int j = pass * 256 + t;
            int k0 = 2 * j, k1 = 2 * j + 1;
            float v0 = row[(k0 & 127) * 8 + (k0 >> 7)];
            float v1 = row[(k1 & 127) * 8 + (k1 >> 7)];
            union { __hip_bfloat16 h[2]; unsigned int u; } pk;
            pk.h[0] = __float2bfloat16(v0);
            pk.h[1] = __float2bfloat16(v1);
            dst[j] = pk.u;
        }
    } else if (b < 3072) {
        int i = (b - 2048) * 256 + t;     // float4 index into w2
        float4 v = *(const float4*)(w2 + (size_t)i * 4);
        union { __hip_bfloat16 h[4]; uint2 u; } pk;
        pk.h[0] = __float2bfloat16(v.x);
        pk.h[1] = __float2bfloat16(v.y);
        pk.h[2] = __float2bfloat16(v.z);
        pk.h[3] = __float2bfloat16(v.w);
        *(uint2*)(w2b + (size_t)i * 4) = pk.u;
    } else {
        int i = (b - 3072) * 256 + t;     // float4 index into w_fc1 (8192 total)
        float4 v = *(const float4*)(wfc1 + (size_t)i * 4);
        union { __hip_bfloat16 h[4]; uint2 u; } pk;
        pk.h[0] = __float2bfloat16(v.x);
        pk.h[1] = __float2bfloat16(v.y);
        pk.h[2] = __float2bfloat16(v.z);
        pk.h[3] = __float2bfloat16(v.w);
        *(uint2*)(wfc1b + (size_t)i * 4) = pk.u;
    }
}

// ---------------------------------------------------------------------------
// Line pool v4 + zero-pad. 256 thr = 2 lines x 2 waves. Blocks whose lines
// are >= N_LINES write zero rows (pads featb to N_PAD rows for 256-tile GEMM).
// feat layout k' = p*128 + c (matches permuted w1).
// ---------------------------------------------------------------------------
__global__ __launch_bounds__(256) void pool_kernel(
    const __hip_bfloat16* __restrict__ loi,   // (NPIX, 128) bf16 channel-last
    const float* __restrict__ lines,          // (N_LINES, 4)
    __hip_bfloat16* __restrict__ feat)        // (N_PAD, 1024), k' = p*128+c
{
    __shared__ int   offs[2][N_PTS0][4];      // uint4-index base (pix*16)
    __shared__ float wts[2][N_PTS0][4];
    const int h     = threadIdx.x >> 7;  // line half of block (0,1)
    const int lt    = threadIdx.x & 127; // thread within line
    const int point = lt >> 4;           // 0..7 output point
    const int t16   = lt & 15;           // channel group 8*t16..8*t16+7
    const int l     = blockIdx.x * 2 + h;

    if (l >= N_LINES) {                  // zero-pad rows [N_LINES, N_PAD)
        uint4 z = {0u, 0u, 0u, 0u};
        uint4* fw = (uint4*)(feat + (size_t)l * (N_PTS1 * DIM_LOI));
        fw[point * 16 + t16] = z;
        return;                          // whole block takes this path (uniform)
    }

    if (lt < N_PTS0) {
        int j = lt;
        float tt = (float)j * (1.0f / 31.0f);
        float U0 = lines[4 * l + 0], U1 = lines[4 * l + 1];
        float V0 = lines[4 * l + 2], V1 = lines[4 * l + 3];
        float px = U0 * tt + V0 * (1.0f - tt) - 0.5f;
        float py = U1 * tt + V1 * (1.0f - tt) - 0.5f;
        float px0 = fminf(fmaxf(floorf(px), 0.0f), 127.0f);
        float py0 = fminf(fmaxf(floorf(py), 0.0f), 127.0f);
        float px1 = fminf(fmaxf(px0 + 1.0f, 0.0f), 127.0f);
        float py1 = fminf(fmaxf(py0 + 1.0f, 0.0f), 127.0f);
        int ix0 = (int)px0, iy0 = (int)py0, ix1 = (int)px1, iy1 = (int)py1;
        float wx0 = px1 - px, wx1 = px - px0;
        float wy0 = py1 - py, wy1 = py - py0;
        offs[h][j][0] = (iy0 * HW + ix0) * 16;
        offs[h][j][1] = (iy1 * HW + ix0) * 16;
        offs[h][j][2] = (iy0 * HW + ix1) * 16;
        offs[h][j][3] = (iy1 * HW + ix1) * 16;
        wts[h][j][0] = wy0 * wx0;
        wts[h][j][1] = wy1 * wx0;
        wts[h][j][2] = wy0 * wx1;
        wts[h][j][3] = wy1 * wx1;
    }
    __syncthreads();

    const uint4* loi4 = (const uint4*)loi;
    uint4* featw = (uint4*)(feat + (size_t)l * (N_PTS1 * DIM_LOI));

    float b0 = -INFINITY, b1 = -INFINITY, b2 = -INFINITY, b3 = -INFINITY;
    float b4 = -INFINITY, b5 = -INFINITY, b6 = -INFINITY, b7 = -INFINITY;
#pragma unroll
    for (int q = 0; q < 4; ++q) {
        int j = point * 4 + q;
        uint4 v0 = loi4[offs[h][j][0] + t16];
        uint4 v1 = loi4[offs[h][j][1] + t16];
        uint4 v2 = loi4[offs[h][j][2] + t16];
        uint4 v3 = loi4[offs[h][j][3] + t16];
        float w0 = wts[h][j][0], w1 = wts[h][j][1];
        float w2 = wts[h][j][2], w3 = wts[h][j][3];
        float s;
        s = w0 * __uint_as_float(v0.x << 16) + w1 * __uint_as_float(v1.x << 16)
          + w2 * __uint_as_float(v2.x << 16) + w3 * __uint_as_float(v3.x << 16);
        b0 = fmaxf(b0, s);
        s = w0 * __uint_as_float(v0.x & 0xffff0000u) + w1 * __uint_as_float(v1.x & 0xffff0000u)
          + w2 * __uint_as_float(v2.x & 0xffff0000u) + w3 * __uint_as_float(v3.x & 0xffff0000u);
        b1 = fmaxf(b1, s);
        s = w0 * __uint_as_float(v0.y << 16) + w1 * __uint_as_float(v1.y << 16)
          + w2 * __uint_as_float(v2.y << 16) + w3 * __uint_as_float(v3.y << 16);
        b2 = fmaxf(b2, s);
        s = w0 * __uint_as_float(v0.y & 0xffff0000u) + w1 * __uint_as_float(v1.y & 0xffff0000u)
          + w2 * __uint_as_float(v2.y & 0xffff0000u) + w3 * __uint_as_float(v3.y & 0xffff0000u);
        b3 = fmaxf(b3, s);
        s = w0 * __uint_as_float(v0.z << 16) + w1 * __uint_as_float(v1.z << 16)
          + w2 * __uint_as_float(v2.z << 16) + w3 * __uint_as_float(v3.z << 16);
        b4 = fmaxf(b4, s);
        s = w0 * __uint_as_float(v0.z & 0xffff0000u) + w1 * __uint_as_float(v1.z & 0xffff0000u)
          + w2 * __uint_as_float(v2.z & 0xffff0000u) + w3 * __uint_as_float(v3.z & 0xffff0000u);
        b5 = fmaxf(b5, s);
        s = w0 * __uint_as_float(v0.w << 16) + w1 * __uint_as_float(v1.w << 16)
          + w2 * __uint_as_float(v2.w << 16) + w3 * __uint_as_float(v3.w << 16);
        b6 = fmaxf(b6, s);
        s = w0 * __uint_as_float(v0.w & 0xffff0000u) + w1 * __uint_as_float(v1.w & 0xffff0000u)
          + w2 * __uint_as_float(v2.w & 0xffff0000u) + w3 * __uint_as_float(v3.w & 0xffff0000u);
        b7 = fmaxf(b7, s);
    }
    union { __hip_bfloat16 hh[8]; uint4 u; } pk;
    pk.hh[0] = __float2bfloat16(b0);
    pk.hh[1] = __float2bfloat16(b1);
    pk.hh[2] = __float2bfloat16(b2);
    pk.hh[3] = __float2bfloat16(b3);
    pk.hh[4] = __float2bfloat16(b4);
    pk.hh[5] = __float2bfloat16(b5);
    pk.hh[6] = __float2bfloat16(b6);
    pk.hh[7] = __float2bfloat16(b7);
    featw[point * 16 + t16] = pk.u;   // elements point*128 + 8*t16 ..+7
}

// ---------------------------------------------------------------------------
// MFMA bf16 GEMM, 128x128 tile, BK=64 dbuf (R12 structure). KEPT for the
// conv1x1 GEMM only (N=128 can't take a 256-wide tile).
// ---------------------------------------------------------------------------
__global__ __launch_bounds__(256) void mfma_gemm(
    const __hip_bfloat16* __restrict__ A,   // (M, K) row-major
    const __hip_bfloat16* __restrict__ B,   // (N, K) row-major (= B^T)
    const float* __restrict__ bias,         // (N)
    __hip_bfloat16* __restrict__ out,       // (M, N)
    int M, int N, int K, int n_tiles)
{
    __shared__ __hip_bfloat16 As[2][128 * 64];   // 32 KB
    __shared__ __hip_bfloat16 Bs[2][128 * 64];   // 32 KB
    const int tid  = threadIdx.x;
    const int lane = tid & 63;
    const int wave = tid >> 6;
    const int wr = wave >> 1, wc = wave & 1;    // 2x2 wave grid
    const int quad = lane >> 4;
    const int l16  = lane & 15;

    // XCD-aware relabel (grid must be divisible by 8)
    const int lid = blockIdx.x;
    const int per = gridDim.x >> 3;
    const int g   = (lid & 7) * per + (lid >> 3);
    const int n0 = (g % n_tiles) * 128;
    const int m0 = (g / n_tiles) * 128;

    f32x4 acc[4][4];
#pragma unroll
    for (int i = 0; i < 4; ++i)
#pragma unroll
        for (int j = 0; j < 4; ++j) { f32x4 z = {0.f, 0.f, 0.f, 0.f}; acc[i][j] = z; }

    auto stage = [&](int k0, int buf) {
#pragma unroll
        for (int s = 0; s < 4; ++s) {
            int li   = s * 256 + tid;          // chunk 0..1023
            int row  = (li & 511) >> 2;        // 0..127
            int ke   = (li >> 9) * 32 + (li & 3) * 8;  // k element offset 0..63
            const __hip_bfloat16* ga = A + (size_t)(m0 + row) * K + k0 + ke;
            const __hip_bfloat16* gb = B + (size_t)(n0 + row) * K + k0 + ke;
            int chunk = s * 256 + (tid & ~63); // wave-uniform base chunk
            __builtin_amdgcn_global_load_lds(
                (const __attribute__((address_space(1))) unsigned int*)ga,
                (__attribute__((address_space(3))) unsigned int*)(As[buf] + chunk * 8),
                16, 0, 0);
            __builtin_amdgcn_global_load_lds(
                (const __attribute__((address_space(1))) unsigned int*)gb,
                (__attribute__((address_space(3))) unsigned int*)(Bs[buf] + chunk * 8),
                16, 0, 0);
        }
    };

    const int nk = K >> 6;
    stage(0, 0);
    __syncthreads();                 // buffer 0 ready

    for (int kt = 0; kt < nk; ++kt) {
        const int cur = kt & 1;
        if (kt + 1 < nk) stage((kt + 1) << 6, cur ^ 1);   // async prefetch

#pragma unroll
        for (int kh = 0; kh < 2; ++kh) {
            const short* ap = (const short*)As[cur] + kh * 4096;
            const short* bp = (const short*)Bs[cur] + kh * 4096;
            short8 af[4], bf[4];
#pragma unroll
            for (int mt = 0; mt < 4; ++mt) {
                int row = wr * 64 + mt * 16 + l16;
                af[mt] = *(const short8*)(ap + row * 32 + quad * 8);
            }
#pragma unroll
            for (int nt = 0; nt < 4; ++nt) {
                int row = wc * 64 + nt * 16 + l16;
                bf[nt] = *(const short8*)(bp + row * 32 + quad * 8);
            }
#pragma unroll
            for (int mt = 0; mt < 4; ++mt)
#pragma unroll
                for (int nt = 0; nt < 4; ++nt)
                    acc[mt][nt] = __builtin_amdgcn_mfma_f32_16x16x32_bf16(
                        af[mt], bf[nt], acc[mt][nt], 0, 0, 0);
        }
        __syncthreads();
    }

#pragma unroll
    for (int nt = 0; nt < 4; ++nt) {
        int n = n0 + wc * 64 + nt * 16 + l16;
        float bv = bias[n];
#pragma unroll
        for (int mt = 0; mt < 4; ++mt) {
            int mbase = m0 + wr * 64 + mt * 16 + quad * 4;
#pragma unroll
            for (int r = 0; r < 4; ++r) {
                float v = acc[mt][nt][r] + bv;
                v = v > 0.0f ? v : 0.0f;
                out[(size_t)(mbase + r) * N + n] = (__hip_bfloat16)v;
            }
        }
    }
}

// ---------------------------------------------------------------------------
// mfma_gemm256: 256x256 tile, BK=64, 8-phase counted-vmcnt schedule.
// R2 changes vs R1 (R1 = 51.5us, FETCH 66.6MB, WRITE 72MB, conflicts 3.1M):
//  (a) bijective XCD swizzle (m204): A-panel + whole B reused within one
//      XCD L2 -> predict FETCH ~36MB and fewer vmcnt stalls.
//  (b) correct bank swizzle: koff ^= (row&7)<<4 (bits 4-6). Each 16-lane
//      quarter-wave covers all 8 16B slots, 2 rows/slot (2-way = free).
//      R1's (row&3)<<5 left 8-way aliasing.
//  (c) LDS-routed epilogue: acc -> LDS (bias+relu, chunk-XOR), barrier,
//      linear read-back, 16B/lane full-line stores (wave = 2 full 512B
//      rows). Kills the partial-line write burst (WRITE 72 -> ~33MB).
// Phase/vmcnt schedule unchanged from R1 (verified passing).
// ---------------------------------------------------------------------------
__global__ __launch_bounds__(512, 2) void mfma_gemm256(
    const __hip_bfloat16* __restrict__ A,   // (M, K) row-major, M % 256 == 0
    const __hip_bfloat16* __restrict__ B,   // (N, K) row-major (= B^T)
    const float* __restrict__ bias,         // (N)
    __hip_bfloat16* __restrict__ out,       // (M, N)
    int M, int N, int K, int n_tiles)
{
    __shared__ __align__(16) short smem[65536];   // 128 KB
    const int tid  = threadIdx.x;
    const int lane = tid & 63;
    const int wave = tid >> 6;              // 0..7
    const int wr   = wave >> 2;             // 0..1 (M wave)
    const int wc   = wave & 3;              // 0..3 (N wave)
    const int quad = lane >> 4;
    const int l16  = lane & 15;

    // bijective XCD swizzle (m204): XCD x gets a contiguous g-range.
    // n fastest in g -> A-panel (4 consecutive g) + whole B live in one L2.
    const int nwg = gridDim.x;
    const int q8  = nwg >> 3, r8 = nwg & 7;
    const int xcd = blockIdx.x & 7;
    const int gb  = (xcd < r8) ? xcd * (q8 + 1) : r8 * (q8 + 1) + (xcd - r8) * q8;
    const int g   = gb + (blockIdx.x >> 3);
    const int n0 = (g % n_tiles) * 256;
    const int m0 = (g / n_tiles) * 256;

    // LDS short offsets: A buf b @ b*16384 ; B buf b @ 32768 + b*16384.
    // Half-tile h of a tile = +h*8192.

    // stage one half-tile (128 rows x 64 k bf16): 2 x 16B per thread,
    // linear LDS dest (uniform base + lane*16), swizzled global source:
    // slot kb within the 128B row holds logical bytes kb ^ ((row&7)<<4).
    auto stageHalf = [&](int dstBase, const __hip_bfloat16* G, int rowG0, int k0) {
#pragma unroll
        for (int j = 0; j < 2; ++j) {
            const int c   = j * 512 + tid;        // chunk 0..1023
            const int row = c >> 3;               // 0..127 (row within half)
            const int kb  = (c & 7) << 4;         // byte 0..112 within row
            const int kbl = kb ^ ((row & 7) << 4);// logical k-byte for this slot
            const __hip_bfloat16* src = G + (size_t)(rowG0 + row) * K + k0 + (kbl >> 1);
            const short* dst = smem + dstBase + j * 4096 + (wave << 9); // wave-uniform
            __builtin_amdgcn_global_load_lds(
                (const __attribute__((address_space(1))) unsigned int*)src,
                (__attribute__((address_space(3))) unsigned int*)dst, 16, 0, 0);
        }
    };

    // fragment reads (swizzle-matched; row&7 == l16&7 for both A and B)
    auto ldA = [&](int buf, int mt, int ks) -> short8 {
        int r    = ((mt >> 2) << 7) + (wr << 6) + ((mt & 3) << 4) + l16;
        int koff = ((ks << 6) + (quad << 4)) ^ ((l16 & 7) << 4);
        return *(const short8*)(smem + buf * 16384 + r * 64 + (koff >> 1));
    };
    auto ldB = [&](int buf, int nt, int ks) -> short8 {
        int r    = (wc << 6) + (nt << 4) + l16;
        int koff = ((ks << 6) + (quad << 4)) ^ ((l16 & 7) << 4);
        return *(const short8*)(smem + 32768 + buf * 16384 + r * 64 + (koff >> 1));
    };

    f32x4 acc[8][4];
#pragma unroll
    for (int i = 0; i < 8; ++i)
#pragma unroll
        for (int j = 0; j < 4; ++j) { f32x4 z = {0.f, 0.f, 0.f, 0.f}; acc[i][j] = z; }

    short8 af[4][2], b01[2][2], b23[2][2];

    const int NT2 = K >> 7;   // iterations of 2 k-tiles; requires NT2 >= 2

    // ---- prologue: tile0 -> buf0 (4 halves), tile1 -> buf1 (A0,B0,A1) ----
    stageHalf(0,                 A, m0,       0);    // A0 t0
    stageHalf(32768,             B, n0,       0);    // B0 t0
    stageHalf(8192,              A, m0 + 128, 0);    // A1 t0
    stageHalf(32768 + 8192,      B, n0 + 128, 0);    // B1 t0
    stageHalf(16384,             A, m0,       64);   // A0 t1
    stageHalf(32768 + 16384,     B, n0,       64);   // B0 t1
    stageHalf(16384 + 8192,      A, m0 + 128, 64);   // A1 t1
    asm volatile("s_waitcnt vmcnt(6)" ::: "memory"); // tile0 landed, t1 in flight
    __builtin_amdgcn_sched_barrier(0);
    __builtin_amdgcn_s_barrier();

#pragma unroll 1
    for (int it = 0; it < NT2; ++it) {
        const bool more = (it + 1 < NT2);
        const int kc1 = (2 * it + 1) << 6;   // buf1 current tile k-base
        const int kn0 = (2 * it + 2) << 6;   // next buf0 tile
        const int kn1 = (2 * it + 3) << 6;   // next buf1 tile

        // ---------- p1: buf0 (m0-3 x n0-1) ----------
#pragma unroll
        for (int mt = 0; mt < 4; ++mt) { af[mt][0] = ldA(0, mt, 0); af[mt][1] = ldA(0, mt, 1); }
#pragma unroll
        for (int nt = 0; nt < 2; ++nt) { b01[nt][0] = ldB(0, nt, 0); b01[nt][1] = ldB(0, nt, 1); }
        stageHalf(32768 + 16384 + 8192, B, n0 + 128, kc1);    // B1 of buf1 tile
        __builtin_amdgcn_s_barrier();
        asm volatile("s_waitcnt lgkmcnt(0)" ::: "memory");
        __builtin_amdgcn_sched_barrier(0);
        __builtin_amdgcn_s_setprio(1);
#pragma unroll
        for (int ks = 0; ks < 2; ++ks)
#pragma unroll
            for (int mt = 0; mt < 4; ++mt)
#pragma unroll
                for (int nt = 0; nt < 2; ++nt)
                    acc[mt][nt] = __builtin_amdgcn_mfma_f32_16x16x32_bf16(
                        af[mt][ks], b01[nt][ks], acc[mt][nt], 0, 0, 0);
        __builtin_amdgcn_s_setprio(0);
        __builtin_amdgcn_s_barrier();

        // ---------- p2: buf0 (m0-3 x n2-3) ----------
#pragma unroll
        for (int nt = 0; nt < 2; ++nt) { b23[nt][0] = ldB(0, nt + 2, 0); b23[nt][1] = ldB(0, nt + 2, 1); }
        if (more) stageHalf(0, A, m0, kn0);                   // A0 next -> buf0
        __builtin_amdgcn_s_barrier();
        asm volatile("s_waitcnt lgkmcnt(0)" ::: "memory");
        __builtin_amdgcn_sched_barrier(0);
        __builtin_amdgcn_s_setprio(1);
#pragma unroll
        for (int ks = 0; ks < 2; ++ks)
#pragma unroll
            for (int mt = 0; mt < 4; ++mt)
#pragma unroll
                for (int nt = 0; nt < 2; ++nt)
                    acc[mt][nt + 2] = __builtin_amdgcn_mfma_f32_16x16x32_bf16(
                        af[mt][ks], b23[nt][ks], acc[mt][nt + 2], 0, 0, 0);
        __builtin_amdgcn_s_setprio(0);
        __builtin_amdgcn_s_barrier();

        // ---------- p3: buf0 (m4-7 x n0-1) ----------
#pragma unroll
        for (int mt = 0; mt < 4; ++mt) { af[mt][0] = ldA(0, mt + 4, 0); af[mt][1] = ldA(0, mt + 4, 1); }
        if (more) stageHalf(32768, B, n0, kn0);               // B0 next -> buf0
        __builtin_amdgcn_s_barrier();
        asm volatile("s_waitcnt lgkmcnt(0)" ::: "memory");
        __builtin_amdgcn_sched_barrier(0);
        __builtin_amdgcn_s_setprio(1);
#pragma unroll
        for (int ks = 0; ks < 2; ++ks)
#pragma unroll
            for (int mt = 0; mt < 4; ++mt)
#pragma unroll
                for (int nt = 0; nt < 2; ++nt)
                    acc[mt + 4][nt] = __builtin_amdgcn_mfma_f32_16x16x32_bf16(
                        af[mt][ks], b01[nt][ks], acc[mt + 4][nt], 0, 0, 0);
        __builtin_amdgcn_s_setprio(0);
        __builtin_amdgcn_s_barrier();

        // ---------- p4: buf0 (m4-7 x n2-3) + K-tile drain ----------
        if (more) stageHalf(8192, A, m0 + 128, kn0);          // A1 next -> buf0
        __builtin_amdgcn_s_barrier();
        asm volatile("s_waitcnt lgkmcnt(0)" ::: "memory");
        __builtin_amdgcn_sched_barrier(0);
        __builtin_amdgcn_s_setprio(1);
#pragma unroll
        for (int ks = 0; ks < 2; ++ks)
#pragma unroll
            for (int mt = 0; mt < 4; ++mt)
#pragma unroll
                for (int nt = 0; nt < 2; ++nt)
                    acc[mt + 4][nt + 2] = __builtin_amdgcn_mfma_f32_16x16x32_bf16(
                        af[mt][ks], b23[nt][ks], acc[mt + 4][nt + 2], 0, 0, 0);
        __builtin_amdgcn_s_setprio(0);
        if (more) { asm volatile("s_waitcnt vmcnt(6)" ::: "memory"); }
        else      { asm volatile("s_waitcnt vmcnt(0)" ::: "memory"); }
        __builtin_amdgcn_sched_barrier(0);
        __builtin_amdgcn_s_barrier();    // buf1 tile (2it+1) fully landed

        // ---------- p5: buf1 (m0-3 x n0-1) ----------
#pragma unroll
        for (int mt = 0; mt < 4; ++mt) { af[mt][0] = ldA(1, mt, 0); af[mt][1] = ldA(1, mt, 1); }
#pragma unroll
        for (int nt = 0; nt < 2; ++nt) { b01[nt][0] = ldB(1, nt, 0); b01[nt][1] = ldB(1, nt, 1); }
        if (more) stageHalf(32768 + 8192, B, n0 + 128, kn0);  // B1 next -> buf0
        __builtin_amdgcn_s_barrier();
        asm volatile("s_waitcnt lgkmcnt(0)" ::: "memory");
        __builtin_amdgcn_sched_barrier(0);
        __builtin_amdgcn_s_setprio(1);
#pragma unroll
        for (int ks = 0; ks < 2; ++ks)
#pragma unroll
            for (int mt = 0; mt < 4; ++mt)
#pragma unroll
                for (int nt = 0; nt < 2; ++nt)
                    acc[mt][nt] = __builtin_amdgcn_mfma_f32_16x16x32_bf16(
                        af[mt][ks], b01[nt][ks], acc[mt][nt], 0, 0, 0);
        __builtin_amdgcn_s_setprio(0);
        __builtin_amdgcn_s_barrier();

        // ---------- p6: buf1 (m0-3 x n2-3) ----------
#pragma unroll
        for (int nt = 0; nt < 2; ++nt) { b23[nt][0] = ldB(1, nt + 2, 0); b23[nt][1] = ldB(1, nt + 2, 1); }
        if (more) stageHalf(16384, A, m0, kn1);               // A0 next -> buf1
        __builtin_amdgcn_s_barrier();
        asm volatile("s_waitcnt lgkmcnt(0)" ::: "memory");
        __builtin_amdgcn_sched_barrier(0);
        __builtin_amdgcn_s_setprio(1);
#pragma unroll
        for (int ks = 0; ks < 2; ++ks)
#pragma unroll
            for (int mt = 0; mt < 4; ++mt)
#pragma unroll
                for (int nt = 0; nt < 2; ++nt)
                    acc[mt][nt + 2] = __builtin_amdgcn_mfma_f32_16x16x32_bf16(
                        af[mt][ks], b23[nt][ks], acc[mt][nt + 2], 0, 0, 0);
        __builtin_amdgcn_s_setprio(0);
        __builtin_amdgcn_s_barrier();

        // ---------- p7: buf1 (m4-7 x n0-1) ----------
#pragma unroll
        for (int mt = 0; mt < 4; ++mt) { af[mt][0] = ldA(1, mt + 4, 0); af[mt][1] = ldA(1, mt + 4, 1); }
        if (more) stageHalf(32768 + 16384, B, n0, kn1);       // B0 next -> buf1
        __builtin_amdgcn_s_barrier();
        asm volatile("s_waitcnt lgkmcnt(0)" ::: "memory");
        __builtin_amdgcn_sched_barrier(0);
        __builtin_amdgcn_s_setprio(1);
#pragma unroll
        for (int ks = 0; ks < 2; ++ks)
#pragma unroll
            for (int mt = 0; mt < 4; ++mt)
#pragma unroll
                for (int nt = 0; nt < 2; ++nt)
                    acc[mt + 4][nt] = __builtin_amdgcn_mfma_f32_16x16x32_bf16(
                        af[mt][ks], b01[nt][ks], acc[mt + 4][nt], 0, 0, 0);
        __builtin_amdgcn_s_setprio(0);
        __builtin_amdgcn_s_barrier();

        // ---------- p8: buf1 (m4-7 x n2-3) + K-tile drain ----------
        if (more) stageHalf(16384 + 8192, A, m0 + 128, kn1);  // A1 next -> buf1
        __builtin_amdgcn_s_barrier();
        asm volatile("s_waitcnt lgkmcnt(0)" ::: "memory");
        __builtin_amdgcn_sched_barrier(0);
        __builtin_amdgcn_s_setprio(1);
#pragma unroll
        for (int ks = 0; ks < 2; ++ks)
#pragma unroll
            for (int mt = 0; mt < 4; ++mt)
#pragma unroll
                for (int nt = 0; nt < 2; ++nt)
                    acc[mt + 4][nt + 2] = __builtin_amdgcn_mfma_f32_16x16x32_bf16(
                        af[mt][ks], b23[nt][ks], acc[mt + 4][nt + 2], 0, 0, 0);
        __builtin_amdgcn_s_setprio(0);
        if (more) {
            asm volatile("s_waitcnt vmcnt(6)" ::: "memory");  // buf0 tile (2it+2) landed
            __builtin_amdgcn_sched_barrier(0);
        }
        __builtin_amdgcn_s_barrier();
    }

    // ---- epilogue via LDS: full-line coalesced stores ----
    // K-loop done; all waves past final barrier, all ds_reads drained
    // (per-wave lgkmcnt(0) before their MFMAs). Reuse smem as the 256x256
    // bf16 output tile, chunk-swizzled: row r, 16B-chunk c stored at
    // chunk (c ^ (r&7)) to break write/read bank aliasing.
    __syncthreads();
#pragma unroll
    for (int nt = 0; nt < 4; ++nt) {
        int ncol = (wc << 6) + (nt << 4) + l16;        // 0..255
        float bv = bias[n0 + ncol];
#pragma unroll
        for (int mt = 0; mt < 8; ++mt) {
            int rbase = ((mt >> 2) << 7) + (wr << 6) + ((mt & 3) << 4) + (quad << 2);
#pragma unroll
            for (int r = 0; r < 4; ++r) {
                float v = acc[mt][nt][r] + bv;
                v = v > 0.0f ? v : 0.0f;
                int row = rbase + r;
                int chunk = (ncol >> 3) ^ (row & 7);
                union { __hip_bfloat16 h; short s; } cv;
                cv.h = (__hip_bfloat16)v;
                smem[row * 256 + chunk * 8 + (ncol & 7)] = cv.s;
            }
        }
    }
    __syncthreads();
#pragma unroll
    for (int p = 0; p < 16; ++p) {
        int ci  = p * 512 + tid;        // 16B chunk id over the tile (8192)
        int row = ci >> 5;              // 32 chunks per 512B row
        int cg  = ci & 31;
        short8 vv = *(const short8*)(smem + row * 256 + ((cg ^ (row & 7)) << 3));
        *(short8*)(out + (size_t)(m0 + row) * N + n0 + cg * 8) = vv;
    }
}

// ---------------------------------------------------------------------------
// Head: one wave per line, uint4 x-loads (16 B/lane, 2 iters):
// logits[l][n] = sum_k x2[l][k]*w3[n][k] + b3[n]
// ---------------------------------------------------------------------------
__global__ __launch_bounds__(256) void head_kernel(
    const __hip_bfloat16* __restrict__ x2,  // (N_LINES, 1024) bf16
    const float* __restrict__ w3,           // (3, 1024)
    const float* __restrict__ b3,           // (3)
    float* __restrict__ out)                // (N_LINES, 3)
{
    const int gtid = blockIdx.x * blockDim.x + threadIdx.x;
    const int l = gtid >> 6;
    const int lane = threadIdx.x & 63;
    if (l >= N_LINES) return;
    const __hip_bfloat16* xr = x2 + (size_t)l * DIM_FC;
    float s0 = 0.0f, s1 = 0.0f, s2 = 0.0f;
#pragma unroll
    for (int it = 0; it < 2; ++it) {
        int k = it * 512 + lane * 8;
        uint4 xv = *(const uint4*)(xr + k);
        float x[8];
        x[0] = __uint_as_float(xv.x << 16);
        x[1] = __uint_as_float(xv.x & 0xffff0000u);
        x[2] = __uint_as_float(xv.y << 16);
        x[3] = __uint_as_float(xv.y & 0xffff0000u);
        x[4] = __uint_as_float(xv.z << 16);
        x[5] = __uint_as_float(xv.z & 0xffff0000u);
        x[6] = __uint_as_float(xv.w << 16);
        x[7] = __uint_as_float(xv.w & 0xffff0000u);
#pragma unroll
        for (int h = 0; h < 2; ++h) {
            int kk = k + h * 4;
            float4 wa = *(const float4*)(w3 + 0 * DIM_FC + kk);
            float4 wb = *(const float4*)(w3 + 1 * DIM_FC + kk);
            float4 wc = *(const float4*)(w3 + 2 * DIM_FC + kk);
            s0 += x[h*4+0] * wa.x + x[h*4+1] * wa.y + x[h*4+2] * wa.z + x[h*4+3] * wa.w;
            s1 += x[h*4+0] * wb.x + x[h*4+1] * wb.y + x[h*4+2] * wb.z + x[h*4+3] * wb.w;
            s2 += x[h*4+0] * wc.x + x[h*4+1] * wc.y + x[h*4+2] * wc.z + x[h*4+3] * wc.w;
        }
    }
#pragma unroll
    for (int off = 32; off > 0; off >>= 1) {
        s0 += __shfl_xor(s0, off);
        s1 += __shfl_xor(s1, off);
        s2 += __shfl_xor(s2, off);
    }
    if (lane == 0) {
        out[(size_t)l * 3 + 0] = s0 + b3[0];
        out[(size_t)l * 3 + 1] = s1 + b3[1];
        out[(size_t)l * 3 + 2] = s2 + b3[2];
    }
}

// ---------------------------------------------------------------------------
extern "C" void kernel_launch(void* const* d_in, const int* in_sizes, int n_in,
                              void* d_out, int out_size, void* d_ws, size_t ws_size,
                              hipStream_t stream) {
    const float* features = (const float*)d_in[0];  // (1,256,128,128)
    const float* lines    = (const float*)d_in[1];  // (16000,4)
    const float* w_fc1    = (const float*)d_in[2];  // (128,256)
    const float* b_fc1    = (const float*)d_in[3];  // (128)
    const float* w1       = (const float*)d_in[4];  // (1024,1024)
    const float* b1       = (const float*)d_in[5];  // (1024)
    const float* w2       = (const float*)d_in[6];  // (1024,1024)
    const float* b2       = (const float*)d_in[7];  // (1024)
    const float* w3       = (const float*)d_in[8];  // (3,1024)
    const float* b3       = (const float*)d_in[9];  // (3)
    float* out = (float*)d_out;

    char* ws = (char*)d_ws;
    __hip_bfloat16* loi    = (__hip_bfloat16*)ws;
    __hip_bfloat16* featb  = (__hip_bfloat16*)(ws + (size_t)8 * 1024 * 1024);   // N_PAD x 1024
    __hip_bfloat16* x1b    = (__hip_bfloat16*)(ws + (size_t)40 * 1024 * 1024);  // N_PAD x 1024
    __hip_bfloat16* x2b    = featb;   // reuse (featb dead after GEMM1)
    __hip_bfloat16* w1b    = (__hip_bfloat16*)(ws + (size_t)72 * 1024 * 1024);
    __hip_bfloat16* w2b    = (__hip_bfloat16*)(ws + (size_t)74 * 1024 * 1024);
    __hip_bfloat16* featsT = (__hip_bfloat16*)(ws + (size_t)76 * 1024 * 1024);
    __hip_bfloat16* wfc1b  = (__hip_bfloat16*)(ws + (size_t)84 * 1024 * 1024);

    // 0) all prep in one dispatch
    prep_kernel<<<dim3(3104), 256, 0, stream>>>(
        features, featsT, w1, w1b, w2, w2b, w_fc1, wfc1b);

    // 1) conv1x1 as MFMA GEMM (128-tile kernel; N=128)
    mfma_gemm<<<dim3(NPIX / 128), 256, 0, stream>>>(
        featsT, wfc1b, b_fc1, loi, NPIX, DIM_LOI, C_IN, 1);

    // 2) line pooling -> featb (N_PAD,1024) bf16, rows >= N_LINES zeroed
    pool_kernel<<<dim3(N_PAD / 2), 256, 0, stream>>>(loi, lines, featb);

    // 3) x1 = relu(feat @ w1p^T + b1): 63 m-tiles x 4 n-tiles, 8-phase kernel
    mfma_gemm256<<<dim3((N_PAD / 256) * (DIM_FC / 256)), 512, 0, stream>>>(
        featb, w1b, b1, x1b, N_PAD, DIM_FC, DIM_FC, DIM_FC / 256);

    // 4) x2 = relu(x1 @ w2^T + b2)
    mfma_gemm256<<<dim3((N_PAD / 256) * (DIM_FC / 256)), 512, 0, stream>>>(
        x1b, w2b, b2, x2b, N_PAD, DIM_FC, DIM_FC, DIM_FC / 256);

    // 5) logits = x2 @ w3^T + b3
    head_kernel<<<dim3((N_LINES * 64 + 255) / 256), 256, 0, stream>>>(x2b, w3, b3, out);
}

// Round 3
// 188.405 us; speedup vs baseline: 1.1143x; 1.0419x over previous
//
#include <hip/hip_runtime.h>
#include <hip/hip_bf16.h>
#include <math.h>

// Problem dims (fixed)
#define C_IN 256
#define HW 128          // H = W = 128
#define NPIX (HW*HW)    // 16384
#define DIM_LOI 128
#define N_LINES 16000
#define N_PAD 16128     // 63*256 : M padded for 256-tile GEMM
#define N_PTS0 32
#define N_PTS1 8
#define DIM_FC 1024
#define N_LABELS 3

typedef __attribute__((ext_vector_type(8))) short short8;   // 8 bf16 = 4 VGPRs
typedef __attribute__((ext_vector_type(4))) float f32x4;

// ---------------------------------------------------------------------------
// prep_kernel: all input conversions in ONE dispatch (branch on blockIdx).
//  [0,1024)    : transpose+bf16 features (256,16384) -> featsT (16384,256)
//  [1024,2048) : permute_w1  k=c*8+p -> k'=p*128+c, fp32->bf16
//  [2048,3072) : to_bf16 w2
//  [3072,3104) : to_bf16 w_fc1
// ---------------------------------------------------------------------------
__global__ __launch_bounds__(256) void prep_kernel(
    const float* __restrict__ feats, __hip_bfloat16* __restrict__ featsT,
    const float* __restrict__ w1,    __hip_bfloat16* __restrict__ w1p,
    const float* __restrict__ w2,    __hip_bfloat16* __restrict__ w2b,
    const float* __restrict__ wfc1,  __hip_bfloat16* __restrict__ wfc1b)
{
    __shared__ float tile[64][65];
    const int b = blockIdx.x;
    const int t = threadIdx.x;

    if (b < 1024) {
        // ---- transpose features ----
        const int p0 = (b & 255) * 64;
        const int c0 = (b >> 8) * 64;
#pragma unroll
        for (int i = 0; i < 4; ++i) {
            int c = (t >> 4) + i * 16;
            int p4 = (t & 15) * 4;
            float4 v = *(const float4*)(feats + (size_t)(c0 + c) * NPIX + p0 + p4);
            tile[c][p4 + 0] = v.x;
            tile[c][p4 + 1] = v.y;
            tile[c][p4 + 2] = v.z;
            tile[c][p4 + 3] = v.w;
        }
        __syncthreads();
#pragma unroll
        for (int i = 0; i < 2; ++i) {
            int p = (t >> 3) + i * 32;
            int cc = (t & 7) * 8;
            union { __hip_bfloat16 h[8]; uint4 u4; } pk;
#pragma unroll
            for (int j = 0; j < 8; ++j) pk.h[j] = __float2bfloat16(tile[cc + j][p]);
            *(uint4*)(featsT + (size_t)(p0 + p) * C_IN + c0 + cc) = pk.u4;
        }
    } else if (b < 2048) {
        // ---- permute w1 row ----
        float* row = &tile[0][0];
        const int n = b - 1024;
        ((float4*)row)[t] = ((const float4*)(w1 + (size_t)n * 1024))[t];
        __syncthreads();
        unsigned int* dst = (unsigned int*)(w1p + (size_t)n * 1024);
#pragma unroll
        for (int pass = 0; pass < 2; ++pass) {
            int j = pass * 256 + t;
            int k0 = 2 * j, k1 = 2 * j + 1;
            float v0 = row[(k0 & 127) * 8 + (k0 >> 7)];
            float v1 = row[(k1 & 127) * 8 + (k1 >> 7)];
            union { __hip_bfloat16 h[2]; unsigned int u; } pk;
            pk.h[0] = __float2bfloat16(v0);
            pk.h[1] = __float2bfloat16(v1);
            dst[j] = pk.u;
        }
    } else if (b < 3072) {
        int i = (b - 2048) * 256 + t;     // float4 index into w2
        float4 v = *(const float4*)(w2 + (size_t)i * 4);
        union { __hip_bfloat16 h[4]; uint2 u; } pk;
        pk.h[0] = __float2bfloat16(v.x);
        pk.h[1] = __float2bfloat16(v.y);
        pk.h[2] = __float2bfloat16(v.z);
        pk.h[3] = __float2bfloat16(v.w);
        *(uint2*)(w2b + (size_t)i * 4) = pk.u;
    } else {
        int i = (b - 3072) * 256 + t;     // float4 index into w_fc1 (8192 total)
        float4 v = *(const float4*)(wfc1 + (size_t)i * 4);
        union { __hip_bfloat16 h[4]; uint2 u; } pk;
        pk.h[0] = __float2bfloat16(v.x);
        pk.h[1] = __float2bfloat16(v.y);
        pk.h[2] = __float2bfloat16(v.z);
        pk.h[3] = __float2bfloat16(v.w);
        *(uint2*)(wfc1b + (size_t)i * 4) = pk.u;
    }
}

// ---------------------------------------------------------------------------
// Line pool v4 + zero-pad. 256 thr = 2 lines x 2 waves. Blocks whose lines
// are >= N_LINES write zero rows (pads featb to N_PAD rows for 256-tile GEMM).
// feat layout k' = p*128 + c (matches permuted w1).
// ---------------------------------------------------------------------------
__global__ __launch_bounds__(256) void pool_kernel(
    const __hip_bfloat16* __restrict__ loi,   // (NPIX, 128) bf16 channel-last
    const float* __restrict__ lines,          // (N_LINES, 4)
    __hip_bfloat16* __restrict__ feat)        // (N_PAD, 1024), k' = p*128+c
{
    __shared__ int   offs[2][N_PTS0][4];      // uint4-index base (pix*16)
    __shared__ float wts[2][N_PTS0][4];
    const int h     = threadIdx.x >> 7;  // line half of block (0,1)
    const int lt    = threadIdx.x & 127; // thread within line
    const int point = lt >> 4;           // 0..7 output point
    const int t16   = lt & 15;           // channel group 8*t16..8*t16+7
    const int l     = blockIdx.x * 2 + h;

    if (l >= N_LINES) {                  // zero-pad rows [N_LINES, N_PAD)
        uint4 z = {0u, 0u, 0u, 0u};
        uint4* fw = (uint4*)(feat + (size_t)l * (N_PTS1 * DIM_LOI));
        fw[point * 16 + t16] = z;
        return;                          // whole block takes this path (uniform)
    }

    if (lt < N_PTS0) {
        int j = lt;
        float tt = (float)j * (1.0f / 31.0f);
        float U0 = lines[4 * l + 0], U1 = lines[4 * l + 1];
        float V0 = lines[4 * l + 2], V1 = lines[4 * l + 3];
        float px = U0 * tt + V0 * (1.0f - tt) - 0.5f;
        float py = U1 * tt + V1 * (1.0f - tt) - 0.5f;
        float px0 = fminf(fmaxf(floorf(px), 0.0f), 127.0f);
        float py0 = fminf(fmaxf(floorf(py), 0.0f), 127.0f);
        float px1 = fminf(fmaxf(px0 + 1.0f, 0.0f), 127.0f);
        float py1 = fminf(fmaxf(py0 + 1.0f, 0.0f), 127.0f);
        int ix0 = (int)px0, iy0 = (int)py0, ix1 = (int)px1, iy1 = (int)py1;
        float wx0 = px1 - px, wx1 = px - px0;
        float wy0 = py1 - py, wy1 = py - py0;
        offs[h][j][0] = (iy0 * HW + ix0) * 16;
        offs[h][j][1] = (iy1 * HW + ix0) * 16;
        offs[h][j][2] = (iy0 * HW + ix1) * 16;
        offs[h][j][3] = (iy1 * HW + ix1) * 16;
        wts[h][j][0] = wy0 * wx0;
        wts[h][j][1] = wy1 * wx0;
        wts[h][j][2] = wy0 * wx1;
        wts[h][j][3] = wy1 * wx1;
    }
    __syncthreads();

    const uint4* loi4 = (const uint4*)loi;
    uint4* featw = (uint4*)(feat + (size_t)l * (N_PTS1 * DIM_LOI));

    float b0 = -INFINITY, b1 = -INFINITY, b2 = -INFINITY, b3 = -INFINITY;
    float b4 = -INFINITY, b5 = -INFINITY, b6 = -INFINITY, b7 = -INFINITY;
#pragma unroll
    for (int q = 0; q < 4; ++q) {
        int j = point * 4 + q;
        uint4 v0 = loi4[offs[h][j][0] + t16];
        uint4 v1 = loi4[offs[h][j][1] + t16];
        uint4 v2 = loi4[offs[h][j][2] + t16];
        uint4 v3 = loi4[offs[h][j][3] + t16];
        float w0 = wts[h][j][0], w1 = wts[h][j][1];
        float w2 = wts[h][j][2], w3 = wts[h][j][3];
        float s;
        s = w0 * __uint_as_float(v0.x << 16) + w1 * __uint_as_float(v1.x << 16)
          + w2 * __uint_as_float(v2.x << 16) + w3 * __uint_as_float(v3.x << 16);
        b0 = fmaxf(b0, s);
        s = w0 * __uint_as_float(v0.x & 0xffff0000u) + w1 * __uint_as_float(v1.x & 0xffff0000u)
          + w2 * __uint_as_float(v2.x & 0xffff0000u) + w3 * __uint_as_float(v3.x & 0xffff0000u);
        b1 = fmaxf(b1, s);
        s = w0 * __uint_as_float(v0.y << 16) + w1 * __uint_as_float(v1.y << 16)
          + w2 * __uint_as_float(v2.y << 16) + w3 * __uint_as_float(v3.y << 16);
        b2 = fmaxf(b2, s);
        s = w0 * __uint_as_float(v0.y & 0xffff0000u) + w1 * __uint_as_float(v1.y & 0xffff0000u)
          + w2 * __uint_as_float(v2.y & 0xffff0000u) + w3 * __uint_as_float(v3.y & 0xffff0000u);
        b3 = fmaxf(b3, s);
        s = w0 * __uint_as_float(v0.z << 16) + w1 * __uint_as_float(v1.z << 16)
          + w2 * __uint_as_float(v2.z << 16) + w3 * __uint_as_float(v3.z << 16);
        b4 = fmaxf(b4, s);
        s = w0 * __uint_as_float(v0.z & 0xffff0000u) + w1 * __uint_as_float(v1.z & 0xffff0000u)
          + w2 * __uint_as_float(v2.z & 0xffff0000u) + w3 * __uint_as_float(v3.z & 0xffff0000u);
        b5 = fmaxf(b5, s);
        s = w0 * __uint_as_float(v0.w << 16) + w1 * __uint_as_float(v1.w << 16)
          + w2 * __uint_as_float(v2.w << 16) + w3 * __uint_as_float(v3.w << 16);
        b6 = fmaxf(b6, s);
        s = w0 * __uint_as_float(v0.w & 0xffff0000u) + w1 * __uint_as_float(v1.w & 0xffff0000u)
          + w2 * __uint_as_float(v2.w & 0xffff0000u) + w3 * __uint_as_float(v3.w & 0xffff0000u);
        b7 = fmaxf(b7, s);
    }
    union { __hip_bfloat16 hh[8]; uint4 u; } pk;
    pk.hh[0] = __float2bfloat16(b0);
    pk.hh[1] = __float2bfloat16(b1);
    pk.hh[2] = __float2bfloat16(b2);
    pk.hh[3] = __float2bfloat16(b3);
    pk.hh[4] = __float2bfloat16(b4);
    pk.hh[5] = __float2bfloat16(b5);
    pk.hh[6] = __float2bfloat16(b6);
    pk.hh[7] = __float2bfloat16(b7);
    featw[point * 16 + t16] = pk.u;   // elements point*128 + 8*t16 ..+7
}

// ---------------------------------------------------------------------------
// MFMA bf16 GEMM, 128x128 tile, BK=64 dbuf (R12 structure). KEPT for the
// conv1x1 GEMM only (N=128 can't take a 256-wide tile).
// ---------------------------------------------------------------------------
__global__ __launch_bounds__(256) void mfma_gemm(
    const __hip_bfloat16* __restrict__ A,   // (M, K) row-major
    const __hip_bfloat16* __restrict__ B,   // (N, K) row-major (= B^T)
    const float* __restrict__ bias,         // (N)
    __hip_bfloat16* __restrict__ out,       // (M, N)
    int M, int N, int K, int n_tiles)
{
    __shared__ __hip_bfloat16 As[2][128 * 64];   // 32 KB
    __shared__ __hip_bfloat16 Bs[2][128 * 64];   // 32 KB
    const int tid  = threadIdx.x;
    const int lane = tid & 63;
    const int wave = tid >> 6;
    const int wr = wave >> 1, wc = wave & 1;    // 2x2 wave grid
    const int quad = lane >> 4;
    const int l16  = lane & 15;

    // XCD-aware relabel (grid must be divisible by 8)
    const int lid = blockIdx.x;
    const int per = gridDim.x >> 3;
    const int g   = (lid & 7) * per + (lid >> 3);
    const int n0 = (g % n_tiles) * 128;
    const int m0 = (g / n_tiles) * 128;

    f32x4 acc[4][4];
#pragma unroll
    for (int i = 0; i < 4; ++i)
#pragma unroll
        for (int j = 0; j < 4; ++j) { f32x4 z = {0.f, 0.f, 0.f, 0.f}; acc[i][j] = z; }

    auto stage = [&](int k0, int buf) {
#pragma unroll
        for (int s = 0; s < 4; ++s) {
            int li   = s * 256 + tid;          // chunk 0..1023
            int row  = (li & 511) >> 2;        // 0..127
            int ke   = (li >> 9) * 32 + (li & 3) * 8;  // k element offset 0..63
            const __hip_bfloat16* ga = A + (size_t)(m0 + row) * K + k0 + ke;
            const __hip_bfloat16* gb = B + (size_t)(n0 + row) * K + k0 + ke;
            int chunk = s * 256 + (tid & ~63); // wave-uniform base chunk
            __builtin_amdgcn_global_load_lds(
                (const __attribute__((address_space(1))) unsigned int*)ga,
                (__attribute__((address_space(3))) unsigned int*)(As[buf] + chunk * 8),
                16, 0, 0);
            __builtin_amdgcn_global_load_lds(
                (const __attribute__((address_space(1))) unsigned int*)gb,
                (__attribute__((address_space(3))) unsigned int*)(Bs[buf] + chunk * 8),
                16, 0, 0);
        }
    };

    const int nk = K >> 6;
    stage(0, 0);
    __syncthreads();                 // buffer 0 ready

    for (int kt = 0; kt < nk; ++kt) {
        const int cur = kt & 1;
        if (kt + 1 < nk) stage((kt + 1) << 6, cur ^ 1);   // async prefetch

#pragma unroll
        for (int kh = 0; kh < 2; ++kh) {
            const short* ap = (const short*)As[cur] + kh * 4096;
            const short* bp = (const short*)Bs[cur] + kh * 4096;
            short8 af[4], bf[4];
#pragma unroll
            for (int mt = 0; mt < 4; ++mt) {
                int row = wr * 64 + mt * 16 + l16;
                af[mt] = *(const short8*)(ap + row * 32 + quad * 8);
            }
#pragma unroll
            for (int nt = 0; nt < 4; ++nt) {
                int row = wc * 64 + nt * 16 + l16;
                bf[nt] = *(const short8*)(bp + row * 32 + quad * 8);
            }
#pragma unroll
            for (int mt = 0; mt < 4; ++mt)
#pragma unroll
                for (int nt = 0; nt < 4; ++nt)
                    acc[mt][nt] = __builtin_amdgcn_mfma_f32_16x16x32_bf16(
                        af[mt], bf[nt], acc[mt][nt], 0, 0, 0);
        }
        __syncthreads();
    }

#pragma unroll
    for (int nt = 0; nt < 4; ++nt) {
        int n = n0 + wc * 64 + nt * 16 + l16;
        float bv = bias[n];
#pragma unroll
        for (int mt = 0; mt < 4; ++mt) {
            int mbase = m0 + wr * 64 + mt * 16 + quad * 4;
#pragma unroll
            for (int r = 0; r < 4; ++r) {
                float v = acc[mt][nt][r] + bv;
                v = v > 0.0f ? v : 0.0f;
                out[(size_t)(mbase + r) * N + n] = (__hip_bfloat16)v;
            }
        }
    }
}

// ---------------------------------------------------------------------------
// K-loop macro shared by mfma_gemm256 (tile-store epilogue) and
// mfma_gemm256_head (fused-head epilogue). Structure is R2-verified:
// 256x256 tile, BK=64, 8-phase counted-vmcnt, bank swizzle (row&7)<<4,
// bijective XCD swizzle, conflicts measured 0.
// ---------------------------------------------------------------------------
#define GEMM256_PROLOG_AND_KLOOP                                              \
    const int tid  = threadIdx.x;                                             \
    const int lane = tid & 63;                                                \
    const int wave = tid >> 6;                                                \
    const int wr   = wave >> 2;                                               \
    const int wc   = wave & 3;                                                \
    const int quad = lane >> 4;                                               \
    const int l16  = lane & 15;                                               \
    const int nwg = gridDim.x;                                                \
    const int q8  = nwg >> 3, r8 = nwg & 7;                                   \
    const int xcd = blockIdx.x & 7;                                           \
    const int gb  = (xcd < r8) ? xcd * (q8 + 1) : r8 * (q8 + 1) + (xcd - r8) * q8; \
    const int g   = gb + (blockIdx.x >> 3);                                   \
    const int n0 = (g % n_tiles) * 256;                                       \
    const int m0 = (g / n_tiles) * 256;                                       \
    auto stageHalf = [&](int dstBase, const __hip_bfloat16* G, int rowG0, int k0) { \
        _Pragma("unroll")                                                     \
        for (int j = 0; j < 2; ++j) {                                         \
            const int c   = j * 512 + tid;                                    \
            const int row = c >> 3;                                           \
            const int kb  = (c & 7) << 4;                                     \
            const int kbl = kb ^ ((row & 7) << 4);                            \
            const __hip_bfloat16* src = G + (size_t)(rowG0 + row) * K + k0 + (kbl >> 1); \
            const short* dst = smem + dstBase + j * 4096 + (wave << 9);       \
            __builtin_amdgcn_global_load_lds(                                 \
                (const __attribute__((address_space(1))) unsigned int*)src,   \
                (__attribute__((address_space(3))) unsigned int*)dst, 16, 0, 0); \
        }                                                                     \
    };                                                                        \
    auto ldA = [&](int buf, int mt, int ks) -> short8 {                       \
        int r    = ((mt >> 2) << 7) + (wr << 6) + ((mt & 3) << 4) + l16;      \
        int koff = ((ks << 6) + (quad << 4)) ^ ((l16 & 7) << 4);              \
        return *(const short8*)(smem + buf * 16384 + r * 64 + (koff >> 1));   \
    };                                                                        \
    auto ldB = [&](int buf, int nt, int ks) -> short8 {                       \
        int r    = (wc << 6) + (nt << 4) + l16;                               \
        int koff = ((ks << 6) + (quad << 4)) ^ ((l16 & 7) << 4);              \
        return *(const short8*)(smem + 32768 + buf * 16384 + r * 64 + (koff >> 1)); \
    };                                                                        \
    f32x4 acc[8][4];                                                          \
    _Pragma("unroll")                                                         \
    for (int i = 0; i < 8; ++i)                                               \
        _Pragma("unroll")                                                     \
        for (int j = 0; j < 4; ++j) { f32x4 z = {0.f, 0.f, 0.f, 0.f}; acc[i][j] = z; } \
    short8 af[4][2], b01[2][2], b23[2][2];                                    \
    const int NT2 = K >> 7;                                                   \
    stageHalf(0,                 A, m0,       0);                             \
    stageHalf(32768,             B, n0,       0);                             \
    stageHalf(8192,              A, m0 + 128, 0);                             \
    stageHalf(32768 + 8192,      B, n0 + 128, 0);                             \
    stageHalf(16384,             A, m0,       64);                            \
    stageHalf(32768 + 16384,     B, n0,       64);                            \
    stageHalf(16384 + 8192,      A, m0 + 128, 64);                            \
    asm volatile("s_waitcnt vmcnt(6)" ::: "memory");                          \
    __builtin_amdgcn_sched_barrier(0);                                        \
    __builtin_amdgcn_s_barrier();                                             \
    _Pragma("unroll 1")                                                       \
    for (int it = 0; it < NT2; ++it) {                                        \
        const bool more = (it + 1 < NT2);                                     \
        const int kc1 = (2 * it + 1) << 6;                                    \
        const int kn0 = (2 * it + 2) << 6;                                    \
        const int kn1 = (2 * it + 3) << 6;                                    \
        /* p1 */                                                              \
        _Pragma("unroll")                                                     \
        for (int mt = 0; mt < 4; ++mt) { af[mt][0] = ldA(0, mt, 0); af[mt][1] = ldA(0, mt, 1); } \
        _Pragma("unroll")                                                     \
        for (int nt = 0; nt < 2; ++nt) { b01[nt][0] = ldB(0, nt, 0); b01[nt][1] = ldB(0, nt, 1); } \
        stageHalf(32768 + 16384 + 8192, B, n0 + 128, kc1);                    \
        __builtin_amdgcn_s_barrier();                                         \
        asm volatile("s_waitcnt lgkmcnt(0)" ::: "memory");                    \
        __builtin_amdgcn_sched_barrier(0);                                    \
        __builtin_amdgcn_s_setprio(1);                                        \
        _Pragma("unroll")                                                     \
        for (int ks = 0; ks < 2; ++ks)                                        \
            _Pragma("unroll")                                                 \
            for (int mt = 0; mt < 4; ++mt)                                    \
                _Pragma("unroll")                                             \
                for (int nt = 0; nt < 2; ++nt)                                \
                    acc[mt][nt] = __builtin_amdgcn_mfma_f32_16x16x32_bf16(    \
                        af[mt][ks], b01[nt][ks], acc[mt][nt], 0, 0, 0);       \
        __builtin_amdgcn_s_setprio(0);                                        \
        __builtin_amdgcn_s_barrier();                                         \
        /* p2 */                                                              \
        _Pragma("unroll")                                                     \
        for (int nt = 0; nt < 2; ++nt) { b23[nt][0] = ldB(0, nt + 2, 0); b23[nt][1] = ldB(0, nt + 2, 1); } \
        if (more) stageHalf(0, A, m0, kn0);                                   \
        __builtin_amdgcn_s_barrier();                                         \
        asm volatile("s_waitcnt lgkmcnt(0)" ::: "memory");                    \
        __builtin_amdgcn_sched_barrier(0);                                    \
        __builtin_amdgcn_s_setprio(1);                                        \
        _Pragma("unroll")                                                     \
        for (int ks = 0; ks < 2; ++ks)                                        \
            _Pragma("unroll")                                                 \
            for (int mt = 0; mt < 4; ++mt)                                    \
                _Pragma("unroll")                                             \
                for (int nt = 0; nt < 2; ++nt)                                \
                    acc[mt][nt + 2] = __builtin_amdgcn_mfma_f32_16x16x32_bf16( \
                        af[mt][ks], b23[nt][ks], acc[mt][nt + 2], 0, 0, 0);   \
        __builtin_amdgcn_s_setprio(0);                                        \
        __builtin_amdgcn_s_barrier();                                         \
        /* p3 */                                                              \
        _Pragma("unroll")                                                     \
        for (int mt = 0; mt < 4; ++mt) { af[mt][0] = ldA(0, mt + 4, 0); af[mt][1] = ldA(0, mt + 4, 1); } \
        if (more) stageHalf(32768, B, n0, kn0);                               \
        __builtin_amdgcn_s_barrier();                                         \
        asm volatile("s_waitcnt lgkmcnt(0)" ::: "memory");                    \
        __builtin_amdgcn_sched_barrier(0);                                    \
        __builtin_amdgcn_s_setprio(1);                                        \
        _Pragma("unroll")                                                     \
        for (int ks = 0; ks < 2; ++ks)                                        \
            _Pragma("unroll")                                                 \
            for (int mt = 0; mt < 4; ++mt)                                    \
                _Pragma("unroll")                                             \
                for (int nt = 0; nt < 2; ++nt)                                \
                    acc[mt + 4][nt] = __builtin_amdgcn_mfma_f32_16x16x32_bf16( \
                        af[mt][ks], b01[nt][ks], acc[mt + 4][nt], 0, 0, 0);   \
        __builtin_amdgcn_s_setprio(0);                                        \
        __builtin_amdgcn_s_barrier();                                         \
        /* p4 */                                                              \
        if (more) stageHalf(8192, A, m0 + 128, kn0);                          \
        __builtin_amdgcn_s_barrier();                                         \
        asm volatile("s_waitcnt lgkmcnt(0)" ::: "memory");                    \
        __builtin_amdgcn_sched_barrier(0);                                    \
        __builtin_amdgcn_s_setprio(1);                                        \
        _Pragma("unroll")                                                     \
        for (int ks = 0; ks < 2; ++ks)                                        \
            _Pragma("unroll")                                                 \
            for (int mt = 0; mt < 4; ++mt)                                    \
                _Pragma("unroll")                                             \
                for (int nt = 0; nt < 2; ++nt)                                \
                    acc[mt + 4][nt + 2] = __builtin_amdgcn_mfma_f32_16x16x32_bf16( \
                        af[mt][ks], b23[nt][ks], acc[mt + 4][nt + 2], 0, 0, 0); \
        __builtin_amdgcn_s_setprio(0);                                        \
        if (more) { asm volatile("s_waitcnt vmcnt(6)" ::: "memory"); }        \
        else      { asm volatile("s_waitcnt vmcnt(0)" ::: "memory"); }        \
        __builtin_amdgcn_sched_barrier(0);                                    \
        __builtin_amdgcn_s_barrier();                                         \
        /* p5 */                                                              \
        _Pragma("unroll")                                                     \
        for (int mt = 0; mt < 4; ++mt) { af[mt][0] = ldA(1, mt, 0); af[mt][1] = ldA(1, mt, 1); } \
        _Pragma("unroll")                                                     \
        for (int nt = 0; nt < 2; ++nt) { b01[nt][0] = ldB(1, nt, 0); b01[nt][1] = ldB(1, nt, 1); } \
        if (more) stageHalf(32768 + 8192, B, n0 + 128, kn0);                  \
        __builtin_amdgcn_s_barrier();                                         \
        asm volatile("s_waitcnt lgkmcnt(0)" ::: "memory");                    \
        __builtin_amdgcn_sched_barrier(0);                                    \
        __builtin_amdgcn_s_setprio(1);                                        \
        _Pragma("unroll")                                                     \
        for (int ks = 0; ks < 2; ++ks)                                        \
            _Pragma("unroll")                                                 \
            for (int mt = 0; mt < 4; ++mt)                                    \
                _Pragma("unroll")                                             \
                for (int nt = 0; nt < 2; ++nt)                                \
                    acc[mt][nt] = __builtin_amdgcn_mfma_f32_16x16x32_bf16(    \
                        af[mt][ks], b01[nt][ks], acc[mt][nt], 0, 0, 0);       \
        __builtin_amdgcn_s_setprio(0);                                        \
        __builtin_amdgcn_s_barrier();                                         \
        /* p6 */                                                              \
        _Pragma("unroll")                                                     \
        for (int nt = 0; nt < 2; ++nt) { b23[nt][0] = ldB(1, nt + 2, 0); b23[nt][1] = ldB(1, nt + 2, 1); } \
        if (more) stageHalf(16384, A, m0, kn1);                               \
        __builtin_amdgcn_s_barrier();                                         \
        asm volatile("s_waitcnt lgkmcnt(0)" ::: "memory");                    \
        __builtin_amdgcn_sched_barrier(0);                                    \
        __builtin_amdgcn_s_setprio(1);                                        \
        _Pragma("unroll")                                                     \
        for (int ks = 0; ks < 2; ++ks)                                        \
            _Pragma("unroll")                                                 \
            for (int mt = 0; mt < 4; ++mt)                                    \
                _Pragma("unroll")                                             \
                for (int nt = 0; nt < 2; ++nt)                                \
                    acc[mt][nt + 2] = __builtin_amdgcn_mfma_f32_16x16x32_bf16( \
                        af[mt][ks], b23[nt][ks], acc[mt][nt + 2], 0, 0, 0);   \
        __builtin_amdgcn_s_setprio(0);                                        \
        __builtin_amdgcn_s_barrier();                                         \
        /* p7 */                                                              \
        _Pragma("unroll")                                                     \
        for (int mt = 0; mt < 4; ++mt) { af[mt][0] = ldA(1, mt + 4, 0); af[mt][1] = ldA(1, mt + 4, 1); } \
        if (more) stageHalf(32768 + 16384, B, n0, kn1);                       \
        __builtin_amdgcn_s_barrier();                                         \
        asm volatile("s_waitcnt lgkmcnt(0)" ::: "memory");                    \
        __builtin_amdgcn_sched_barrier(0);                                    \
        __builtin_amdgcn_s_setprio(1);                                        \
        _Pragma("unroll")                                                     \
        for (int ks = 0; ks < 2; ++ks)                                        \
            _Pragma("unroll")                                                 \
            for (int mt = 0; mt < 4; ++mt)                                    \
                _Pragma("unroll")                                             \
                for (int nt = 0; nt < 2; ++nt)                                \
                    acc[mt + 4][nt] = __builtin_amdgcn_mfma_f32_16x16x32_bf16( \
                        af[mt][ks], b01[nt][ks], acc[mt + 4][nt], 0, 0, 0);   \
        __builtin_amdgcn_s_setprio(0);                                        \
        __builtin_amdgcn_s_barrier();                                         \
        /* p8 */                                                              \
        if (more) stageHalf(16384 + 8192, A, m0 + 128, kn1);                  \
        __builtin_amdgcn_s_barrier();                                         \
        asm volatile("s_waitcnt lgkmcnt(0)" ::: "memory");                    \
        __builtin_amdgcn_sched_barrier(0);                                    \
        __builtin_amdgcn_s_setprio(1);                                        \
        _Pragma("unroll")                                                     \
        for (int ks = 0; ks < 2; ++ks)                                        \
            _Pragma("unroll")                                                 \
            for (int mt = 0; mt < 4; ++mt)                                    \
                _Pragma("unroll")                                             \
                for (int nt = 0; nt < 2; ++nt)                                \
                    acc[mt + 4][nt + 2] = __builtin_amdgcn_mfma_f32_16x16x32_bf16( \
                        af[mt][ks], b23[nt][ks], acc[mt + 4][nt + 2], 0, 0, 0); \
        __builtin_amdgcn_s_setprio(0);                                        \
        if (more) {                                                           \
            asm volatile("s_waitcnt vmcnt(6)" ::: "memory");                  \
            __builtin_amdgcn_sched_barrier(0);                                \
        }                                                                     \
        __builtin_amdgcn_s_barrier();                                         \
    }

// ---------------------------------------------------------------------------
// mfma_gemm256: R2-verified kernel (tile-store epilogue via LDS).
// Used for GEMM1 (x1 = relu(feat @ w1^T + b1)) whose output feeds GEMM2.
// ---------------------------------------------------------------------------
__global__ __launch_bounds__(512, 2) void mfma_gemm256(
    const __hip_bfloat16* __restrict__ A,   // (M, K) row-major, M % 256 == 0
    const __hip_bfloat16* __restrict__ B,   // (N, K) row-major (= B^T)
    const float* __restrict__ bias,         // (N)
    __hip_bfloat16* __restrict__ out,       // (M, N)
    int M, int N, int K, int n_tiles)
{
    __shared__ __align__(16) short smem[65536];   // 128 KB
    GEMM256_PROLOG_AND_KLOOP

    // ---- epilogue via LDS: full-line coalesced stores ----
    __syncthreads();
#pragma unroll
    for (int nt = 0; nt < 4; ++nt) {
        int ncol = (wc << 6) + (nt << 4) + l16;        // 0..255
        float bv = bias[n0 + ncol];
#pragma unroll
        for (int mt = 0; mt < 8; ++mt) {
            int rbase = ((mt >> 2) << 7) + (wr << 6) + ((mt & 3) << 4) + (quad << 2);
#pragma unroll
            for (int r = 0; r < 4; ++r) {
                float v = acc[mt][nt][r] + bv;
                v = v > 0.0f ? v : 0.0f;
                int row = rbase + r;
                int chunk = (ncol >> 3) ^ (row & 7);
                union { __hip_bfloat16 h; short s; } cv;
                cv.h = (__hip_bfloat16)v;
                smem[row * 256 + chunk * 8 + (ncol & 7)] = cv.s;
            }
        }
    }
    __syncthreads();
#pragma unroll
    for (int p = 0; p < 16; ++p) {
        int ci  = p * 512 + tid;        // 16B chunk id over the tile (8192)
        int row = ci >> 5;              // 32 chunks per 512B row
        int cg  = ci & 31;
        short8 vv = *(const short8*)(smem + row * 256 + ((cg ^ (row & 7)) << 3));
        *(short8*)(out + (size_t)(m0 + row) * N + n0 + cg * 8) = vv;
    }
}

// ---------------------------------------------------------------------------
// mfma_gemm256_head: same K-loop; epilogue fuses the N_LABELS=3 head:
//   pl[nblk][m0+row][lbl] = sum_{n in this block's 256 cols}
//                              relu(acc + b2[n]) * w3[lbl][n]
// x2 is never materialized (saves 32MB store + 33MB head re-read).
// Reduction: per-thread over its 4 cols -> shfl_xor over l16 (16 lanes) ->
// LDS scratch over wc (4 waves) -> 256 threads write fp32 partials.
// ---------------------------------------------------------------------------
__global__ __launch_bounds__(512, 2) void mfma_gemm256_head(
    const __hip_bfloat16* __restrict__ A,   // (M, K) x1, row-major
    const __hip_bfloat16* __restrict__ B,   // (N, K) w2 (= B^T)
    const float* __restrict__ bias,         // (N) b2
    const float* __restrict__ w3,           // (3, DIM_FC)
    float* __restrict__ pl,                 // (4, N_PAD*3) partial logits
    int M, int N, int K, int n_tiles)
{
    __shared__ __align__(16) short smem[65536];   // 128 KB (K-loop), then scratch
    GEMM256_PROLOG_AND_KLOOP

    // ---- fused head epilogue ----
    const int nblk = n0 >> 8;   // 0..3 (n_tiles == 4)
    float w3v[3][4];
    float bv[4];
#pragma unroll
    for (int nt = 0; nt < 4; ++nt) {
        int n = n0 + (wc << 6) + (nt << 4) + l16;
        bv[nt] = bias[n];
#pragma unroll
        for (int lbl = 0; lbl < 3; ++lbl) w3v[lbl][nt] = w3[lbl * DIM_FC + n];
    }

    float* scratch = (float*)smem;          // [256 rows][3 lbl][4 wc] = 12 KB
#pragma unroll
    for (int mt = 0; mt < 8; ++mt) {
        int rbase = ((mt >> 2) << 7) + (wr << 6) + ((mt & 3) << 4) + (quad << 2);
#pragma unroll
        for (int r = 0; r < 4; ++r) {
            float s0 = 0.f, s1 = 0.f, s2 = 0.f;
#pragma unroll
            for (int nt = 0; nt < 4; ++nt) {
                float v = acc[mt][nt][r] + bv[nt];
                v = v > 0.0f ? v : 0.0f;
                s0 += v * w3v[0][nt];
                s1 += v * w3v[1][nt];
                s2 += v * w3v[2][nt];
            }
#pragma unroll
            for (int off = 1; off < 16; off <<= 1) {
                s0 += __shfl_xor(s0, off);
                s1 += __shfl_xor(s1, off);
                s2 += __shfl_xor(s2, off);
            }
            if (l16 == 0) {
                int row = rbase + r;
                scratch[row * 12 + 0 * 4 + wc] = s0;
                scratch[row * 12 + 1 * 4 + wc] = s1;
                scratch[row * 12 + 2 * 4 + wc] = s2;
            }
        }
    }
    __syncthreads();
    if (tid < 256) {
        const float* sr = scratch + tid * 12;
        float t0 = sr[0] + sr[1] + sr[2]  + sr[3];
        float t1 = sr[4] + sr[5] + sr[6]  + sr[7];
        float t2 = sr[8] + sr[9] + sr[10] + sr[11];
        float* dst = pl + (size_t)nblk * (N_PAD * 3) + (size_t)(m0 + tid) * 3;
        dst[0] = t0; dst[1] = t1; dst[2] = t2;
    }
}

// ---------------------------------------------------------------------------
// head_sum: out[i] = b3[i%3] + sum_{nb} pl[nb][i], i over N_LINES*3.
// ---------------------------------------------------------------------------
__global__ __launch_bounds__(256) void head_sum(
    const float* __restrict__ pl,   // (4, N_PAD*3)
    const float* __restrict__ b3,   // (3)
    float* __restrict__ out)        // (N_LINES*3)
{
    int i = blockIdx.x * 256 + threadIdx.x;
    if (i >= N_LINES * 3) return;
    float s = b3[i % 3]
            + pl[0 * (N_PAD * 3) + i]
            + pl[1 * (N_PAD * 3) + i]
            + pl[2 * (N_PAD * 3) + i]
            + pl[3 * (N_PAD * 3) + i];
    out[i] = s;
}

// ---------------------------------------------------------------------------
extern "C" void kernel_launch(void* const* d_in, const int* in_sizes, int n_in,
                              void* d_out, int out_size, void* d_ws, size_t ws_size,
                              hipStream_t stream) {
    const float* features = (const float*)d_in[0];  // (1,256,128,128)
    const float* lines    = (const float*)d_in[1];  // (16000,4)
    const float* w_fc1    = (const float*)d_in[2];  // (128,256)
    const float* b_fc1    = (const float*)d_in[3];  // (128)
    const float* w1       = (const float*)d_in[4];  // (1024,1024)
    const float* b1       = (const float*)d_in[5];  // (1024)
    const float* w2       = (const float*)d_in[6];  // (1024,1024)
    const float* b2       = (const float*)d_in[7];  // (1024)
    const float* w3       = (const float*)d_in[8];  // (3,1024)
    const float* b3       = (const float*)d_in[9];  // (3)
    float* out = (float*)d_out;

    char* ws = (char*)d_ws;
    __hip_bfloat16* loi    = (__hip_bfloat16*)ws;
    __hip_bfloat16* featb  = (__hip_bfloat16*)(ws + (size_t)8 * 1024 * 1024);   // N_PAD x 1024
    __hip_bfloat16* x1b    = (__hip_bfloat16*)(ws + (size_t)40 * 1024 * 1024);  // N_PAD x 1024
    __hip_bfloat16* w1b    = (__hip_bfloat16*)(ws + (size_t)72 * 1024 * 1024);
    __hip_bfloat16* w2b    = (__hip_bfloat16*)(ws + (size_t)74 * 1024 * 1024);
    __hip_bfloat16* featsT = (__hip_bfloat16*)(ws + (size_t)76 * 1024 * 1024);
    __hip_bfloat16* wfc1b  = (__hip_bfloat16*)(ws + (size_t)84 * 1024 * 1024);
    float*          plbuf  = (float*)(ws + (size_t)86 * 1024 * 1024);           // 4 x N_PAD x 3 f32

    // 0) all prep in one dispatch
    prep_kernel<<<dim3(3104), 256, 0, stream>>>(
        features, featsT, w1, w1b, w2, w2b, w_fc1, wfc1b);

    // 1) conv1x1 as MFMA GEMM (128-tile kernel; N=128)
    mfma_gemm<<<dim3(NPIX / 128), 256, 0, stream>>>(
        featsT, wfc1b, b_fc1, loi, NPIX, DIM_LOI, C_IN, 1);

    // 2) line pooling -> featb (N_PAD,1024) bf16, rows >= N_LINES zeroed
    pool_kernel<<<dim3(N_PAD / 2), 256, 0, stream>>>(loi, lines, featb);

    // 3) x1 = relu(feat @ w1p^T + b1): 63 m-tiles x 4 n-tiles, 8-phase kernel
    mfma_gemm256<<<dim3((N_PAD / 256) * (DIM_FC / 256)), 512, 0, stream>>>(
        featb, w1b, b1, x1b, N_PAD, DIM_FC, DIM_FC, DIM_FC / 256);

    // 4) x2 = relu(x1 @ w2^T + b2) fused with head partials (x2 not stored)
    mfma_gemm256_head<<<dim3((N_PAD / 256) * (DIM_FC / 256)), 512, 0, stream>>>(
        x1b, w2b, b2, w3, plbuf, N_PAD, DIM_FC, DIM_FC, DIM_FC / 256);

    // 5) logits = sum of partials + b3
    head_sum<<<dim3((N_LINES * 3 + 255) / 256), 256, 0, stream>>>(plbuf, b3, out);
}